// Round 1
// 3222.440 us; speedup vs baseline: 1.3749x; 1.3749x over previous
//
#include <hip/hip_runtime.h>
#include <hip/hip_bf16.h>
#include <math.h>

#define BB 8
#define EE 768
#define HH 12
#define LL 12
#define DD 64
#define MLPD 3072
#define NN 197
#define NPATCH 196
#define NCLS 1000
#define NROWS (BB*NN)        // 1576
#define PROWS (BB*NPATCH)    // 1568
#define MPAD 1664            // 13 * 128
#define HTILES 13            // MPAD/128
#define NBH (BB*HH)          // 96
#define NP224 224
#define NP256 256
#define SCALE 0.125f

#define MODE_F32   0
#define MODE_ELU1F 1
#define MODE_GELUB 2
#define MODE_RESF  3

typedef __attribute__((ext_vector_type(8))) short bf16x8;
typedef __attribute__((ext_vector_type(4))) float f32x4;

__device__ __forceinline__ unsigned short f2b(float f) {
    union { __hip_bfloat16 h; unsigned short u; } x;
    x.h = __float2bfloat16(f);
    return x.u;
}

#define GLD(gptr, lptr) __builtin_amdgcn_global_load_lds( \
    (const __attribute__((address_space(1))) unsigned int*)(gptr), \
    (__attribute__((address_space(3))) unsigned int*)(lptr), 16, 0, 0)

// =============== dual-half MFMA bf16 GEMM ===============
// blockIdx.y in [0,26): half = y>=13 selects {A,W,bias,mode,resid,out} set.
__global__ __launch_bounds__(256) void mfma_gemm2(
    const unsigned short* __restrict__ A0, const unsigned short* __restrict__ A1,
    const unsigned short* __restrict__ W0, const unsigned short* __restrict__ W1,
    const float* __restrict__ bias0, const float* __restrict__ bias1,
    int K, int Nc, int mode0, int mode1,
    const float* __restrict__ gamma,
    const float* __restrict__ resid0, const float* __restrict__ resid1,
    float* __restrict__ Cf0, float* __restrict__ Cf1,
    unsigned short* __restrict__ Cb0, unsigned short* __restrict__ Cb1)
{
    __shared__ unsigned short lA[128 * 32];
    __shared__ unsigned short lB[128 * 32];
    const int tid  = threadIdx.x;
    const int lane = tid & 63;
    const int wave = tid >> 6;
    const int wm = wave >> 1, wn = wave & 1;
    const int half = blockIdx.y >= HTILES;
    const int mout0 = (blockIdx.y - (half ? HTILES : 0)) * 128;
    const int n0 = blockIdx.x * 128;
    const unsigned short* A = half ? A1 : A0;
    const unsigned short* W = half ? W1 : W0;
    const float* bias = half ? bias1 : bias0;
    const float* resid = half ? resid1 : resid0;
    float* Cf = half ? Cf1 : Cf0;
    unsigned short* Cb = half ? Cb1 : Cb0;
    const int mode = half ? mode1 : mode0;

    const int srow  = lane >> 2;
    const int skoff = (lane & 3) * 8;
    const int fr = lane & 15;
    const int fk = (lane >> 4) * 8;

    f32x4 acc[4][4];
#pragma unroll
    for (int i = 0; i < 4; i++)
#pragma unroll
        for (int j = 0; j < 4; j++) acc[i][j] = (f32x4){0.f, 0.f, 0.f, 0.f};

    for (int k0 = 0; k0 < K; k0 += 32) {
#pragma unroll
        for (int i = 0; i < 2; i++) {
            int chunk = wave * 2 + i;
            int row = chunk * 16 + srow;
            GLD(A + (size_t)(mout0 + row) * K + k0 + skoff, lA + chunk * 512);
            GLD(W + (size_t)(n0 + row) * K + k0 + skoff, lB + chunk * 512);
        }
        __syncthreads();
        bf16x8 a[4], b[4];
#pragma unroll
        for (int t = 0; t < 4; t++) {
            a[t] = *(const bf16x8*)(lA + (wm * 64 + t * 16 + fr) * 32 + fk);
            b[t] = *(const bf16x8*)(lB + (wn * 64 + t * 16 + fr) * 32 + fk);
        }
#pragma unroll
        for (int i = 0; i < 4; i++)
#pragma unroll
            for (int j = 0; j < 4; j++)
                acc[i][j] = __builtin_amdgcn_mfma_f32_16x16x32_bf16(a[i], b[j], acc[i][j], 0, 0, 0);
        __syncthreads();
    }

    const int crow0 = mout0 + wm * 64;
    const int ccol0 = n0 + wn * 64;
    const int lr = (lane >> 4) * 4;
    const int lc = lane & 15;
#pragma unroll
    for (int i = 0; i < 4; i++) {
#pragma unroll
        for (int j = 0; j < 4; j++) {
            int col = ccol0 + j * 16 + lc;
            float bv = bias ? bias[col] : 0.f;
#pragma unroll
            for (int r = 0; r < 4; r++) {
                int row = crow0 + i * 16 + lr + r;
                float v = acc[i][j][r] + bv;
                size_t o = (size_t)row * Nc + col;
                if (mode == MODE_ELU1F) {
                    Cf[o] = (v > 0.f) ? (v + 1.f) : expf(v);
                } else if (mode == MODE_GELUB) {
                    v = 0.5f * v * (1.f + erff(v * 0.70710678118654752f));
                    Cb[o] = f2b(v);
                } else if (mode == MODE_RESF) {
                    Cf[o] = resid[o] + gamma[col] * v;
                } else {
                    Cf[o] = v;
                }
            }
        }
    }
}

// =============== split-K dual-half MFMA GEMM: fp32 partials, no epilogue ===============
// grid (Nc/128, 2*HTILES, S). Partial layout: P[(half*S + z)][MPAD][Nc].
// Caller guarantees S*Kc == K and Kc % 32 == 0.
__global__ __launch_bounds__(256) void mfma_gemm2_sk(
    const unsigned short* __restrict__ A0, const unsigned short* __restrict__ A1,
    const unsigned short* __restrict__ W0, const unsigned short* __restrict__ W1,
    int K, int Kc, int Nc, int S,
    float* __restrict__ P)
{
    __shared__ unsigned short lA[128 * 32];
    __shared__ unsigned short lB[128 * 32];
    const int tid  = threadIdx.x;
    const int lane = tid & 63;
    const int wave = tid >> 6;
    const int wm = wave >> 1, wn = wave & 1;
    const int half = blockIdx.y >= HTILES;
    const int mout0 = (blockIdx.y - (half ? HTILES : 0)) * 128;
    const int n0 = blockIdx.x * 128;
    const int z = blockIdx.z;
    const int kb = z * Kc;
    const unsigned short* A = half ? A1 : A0;
    const unsigned short* W = half ? W1 : W0;

    const int srow  = lane >> 2;
    const int skoff = (lane & 3) * 8;
    const int fr = lane & 15;
    const int fk = (lane >> 4) * 8;

    f32x4 acc[4][4];
#pragma unroll
    for (int i = 0; i < 4; i++)
#pragma unroll
        for (int j = 0; j < 4; j++) acc[i][j] = (f32x4){0.f, 0.f, 0.f, 0.f};

    for (int k0 = kb; k0 < kb + Kc; k0 += 32) {
#pragma unroll
        for (int i = 0; i < 2; i++) {
            int chunk = wave * 2 + i;
            int row = chunk * 16 + srow;
            GLD(A + (size_t)(mout0 + row) * K + k0 + skoff, lA + chunk * 512);
            GLD(W + (size_t)(n0 + row) * K + k0 + skoff, lB + chunk * 512);
        }
        __syncthreads();
        bf16x8 a[4], b[4];
#pragma unroll
        for (int t = 0; t < 4; t++) {
            a[t] = *(const bf16x8*)(lA + (wm * 64 + t * 16 + fr) * 32 + fk);
            b[t] = *(const bf16x8*)(lB + (wn * 64 + t * 16 + fr) * 32 + fk);
        }
#pragma unroll
        for (int i = 0; i < 4; i++)
#pragma unroll
            for (int j = 0; j < 4; j++)
                acc[i][j] = __builtin_amdgcn_mfma_f32_16x16x32_bf16(a[i], b[j], acc[i][j], 0, 0, 0);
        __syncthreads();
    }

    float* Pout = P + (size_t)(half * S + z) * MPAD * Nc;
    const int crow0 = mout0 + wm * 64;
    const int ccol0 = n0 + wn * 64;
    const int lr = (lane >> 4) * 4;
    const int lc = lane & 15;
#pragma unroll
    for (int i = 0; i < 4; i++) {
#pragma unroll
        for (int j = 0; j < 4; j++) {
            int col = ccol0 + j * 16 + lc;
#pragma unroll
            for (int r = 0; r < 4; r++) {
                int row = crow0 + i * 16 + lr + r;
                Pout[(size_t)row * Nc + col] = acc[i][j][r];
            }
        }
    }
}

// =============== split-K reduce + fused epilogue (F32 / RESF) ===============
// grid (MPAD*Nc/1024, 2). Vectorized float4; Nc must be a multiple of 4.
__global__ __launch_bounds__(256) void sk_reduce_kernel(
    const float* __restrict__ P, int S, int Nc, int mode,
    const float* __restrict__ bias0, const float* __restrict__ bias1,
    const float* __restrict__ gamma,
    const float* __restrict__ resid0, const float* __restrict__ resid1,
    float* __restrict__ C0, float* __restrict__ C1)
{
    const size_t per = (size_t)MPAD * Nc;
    size_t gi = ((size_t)blockIdx.x * 256 + threadIdx.x) * 4;
    if (gi >= per) return;
    const int half = blockIdx.y;
    const float* p = P + (size_t)half * S * per + gi;
    float4 s = *(const float4*)p;
    for (int z = 1; z < S; z++) {
        float4 q = *(const float4*)(p + (size_t)z * per);
        s.x += q.x; s.y += q.y; s.z += q.z; s.w += q.w;
    }
    const int col = (int)(gi % (size_t)Nc);
    const float* bias = half ? bias1 : bias0;
    float4 bv = *(const float4*)(bias + col);
    s.x += bv.x; s.y += bv.y; s.z += bv.z; s.w += bv.w;
    float* C = half ? C1 : C0;
    if (mode == MODE_RESF) {
        const float* resid = half ? resid1 : resid0;
        float4 rv = *(const float4*)(resid + gi);
        float4 gv = *(const float4*)(gamma + col);
        s.x = rv.x + gv.x * s.x;
        s.y = rv.y + gv.y * s.y;
        s.z = rv.z + gv.z * s.z;
        s.w = rv.w + gv.w * s.w;
    }
    *(float4*)(C + gi) = s;
}

// =============== attention pre: operands + coalesced transpose ===============
__global__ __launch_bounds__(256) void pre_kernel(
    const float* __restrict__ qkv, const float* __restrict__ cqkv,
    unsigned short* __restrict__ Aq, unsigned short* __restrict__ Bk,
    float* __restrict__ rsum, float* __restrict__ csum,
    unsigned short* __restrict__ vT, unsigned short* __restrict__ cvT)
{
    const int t = blockIdx.x;
    const int bh = blockIdx.y;
    const int b = bh / HH, h = bh % HH;
    const int n0 = t * 64;
    const int lane = threadIdx.x & 63;
    const int w = threadIdx.x >> 6;
    __shared__ unsigned short vs[64][66];
    __shared__ unsigned short cvs[64][66];

    for (int p = 0; p < 16; p++) {
        int nl = p * 4 + w;
        int n = n0 + nl;
        int d = lane;
        size_t arow = ((size_t)bh * NP256 + n) * 128;
        if (n < NN) {
            size_t basei = (size_t)(b * NN + n) * 3 * EE + h * DD + d;
            float q  = qkv[basei];
            float k  = qkv[basei + EE];
            float v  = qkv[basei + 2 * EE];
            float cq = cqkv[basei];
            float ck = cqkv[basei + EE];
            float cv = cqkv[basei + 2 * EE];
            float qs = q * SCALE;
            float sqq = sqrtf(fmaxf(cq, 1e-24f));
            float sqk = sqrtf(fmaxf(ck, 1e-24f));
            Aq[arow + d]      = f2b(qs);
            Aq[arow + 64 + d] = f2b(sqq);
            Bk[arow + d]      = f2b(k);
            Bk[arow + 64 + d] = f2b(sqk);
            vs[nl][d]  = f2b(v);
            cvs[nl][d] = f2b(cv);
            float r = qs * qs + cq;
            float c = k * k + ck;
            for (int off2 = 32; off2 > 0; off2 >>= 1) {
                r += __shfl_down(r, off2);
                c += __shfl_down(c, off2);
            }
            if (d == 0) { rsum[bh * NP256 + n] = r; csum[bh * NP256 + n] = c; }
        } else {
            ((unsigned int*)(Aq + arow))[d] = 0u;
            ((unsigned int*)(Bk + arow))[d] = 0u;
            vs[nl][d] = 0; cvs[nl][d] = 0;
            if (d == 0) { rsum[bh * NP256 + n] = 0.f; csum[bh * NP256 + n] = 0.f; }
        }
    }
    __syncthreads();
    for (int p = 0; p < 16; p++) {
        int dr = p * 4 + w;
        int n = n0 + lane;
        if (n < NP224) {
            vT [((size_t)bh * 64 + dr) * NP224 + n] = vs[lane][dr];
            cvT[((size_t)bh * 64 + dr) * NP224 + n] = cvs[lane][dr];
        }
    }
}

// =============== Wasserstein logits via MFMA + fused sigmoid + rpb ===============
__global__ __launch_bounds__(256) void wass_gemm(
    const unsigned short* __restrict__ Aq, const unsigned short* __restrict__ Bk,
    const float* __restrict__ rsum, const float* __restrict__ csum,
    const float* __restrict__ rpb, float* __restrict__ S)
{
    __shared__ unsigned short lA[128 * 32];
    __shared__ unsigned short lB[128 * 32];
    const int tid = threadIdx.x, lane = tid & 63, wave = tid >> 6;
    const int wm = wave >> 1, wn = wave & 1;
    const int bh = blockIdx.z;
    const int h = bh % HH;
    const int m0 = blockIdx.y * 128;
    const int n0 = blockIdx.x * 128;
    const unsigned short* A = Aq + (size_t)bh * NP256 * 128;
    const unsigned short* B = Bk + (size_t)bh * NP256 * 128;
    const int srow = lane >> 2, skoff = (lane & 3) * 8;
    const int fr = lane & 15, fk = (lane >> 4) * 8;

    f32x4 acc[4][4];
#pragma unroll
    for (int i = 0; i < 4; i++)
#pragma unroll
        for (int j = 0; j < 4; j++) acc[i][j] = (f32x4){0.f, 0.f, 0.f, 0.f};

    for (int k0 = 0; k0 < 128; k0 += 32) {
#pragma unroll
        for (int i = 0; i < 2; i++) {
            int chunk = wave * 2 + i;
            int row = chunk * 16 + srow;
            GLD(A + (size_t)(m0 + row) * 128 + k0 + skoff, lA + chunk * 512);
            GLD(B + (size_t)(n0 + row) * 128 + k0 + skoff, lB + chunk * 512);
        }
        __syncthreads();
        bf16x8 a[4], b[4];
#pragma unroll
        for (int t = 0; t < 4; t++) {
            a[t] = *(const bf16x8*)(lA + (wm * 64 + t * 16 + fr) * 32 + fk);
            b[t] = *(const bf16x8*)(lB + (wn * 64 + t * 16 + fr) * 32 + fk);
        }
#pragma unroll
        for (int i = 0; i < 4; i++)
#pragma unroll
            for (int j = 0; j < 4; j++)
                acc[i][j] = __builtin_amdgcn_mfma_f32_16x16x32_bf16(a[i], b[j], acc[i][j], 0, 0, 0);
        __syncthreads();
    }

    const int lr = (lane >> 4) * 4;
    const int lc = lane & 15;
#pragma unroll
    for (int i = 0; i < 4; i++) {
#pragma unroll
        for (int j = 0; j < 4; j++) {
            int m = n0 + wn * 64 + j * 16 + lc;
            float cs = csum[bh * NP256 + m];
#pragma unroll
            for (int r = 0; r < 4; r++) {
                int n = m0 + wm * 64 + i * 16 + lr + r;
                float z = 2.f * acc[i][j][r] - rsum[bh * NP256 + n] - cs + 1e-24f;
                float s = 1.f / (1.f + expf(-z));
                float rp = (n < NN && m < NN) ? rpb[((size_t)h * NN + n) * NN + m] : 0.f;
                S[((size_t)bh * NP256 + n) * NP256 + m] = s + rp;
            }
        }
    }
}

// =============== softmax over m; emit bf16 attn and attn^2 ===============
__global__ __launch_bounds__(256) void softmax_kernel(
    const float* __restrict__ S, unsigned short* __restrict__ Ab,
    unsigned short* __restrict__ A2b)
{
    const int wave = threadIdx.x >> 6, lane = threadIdx.x & 63;
    const int idx = blockIdx.x * 4 + wave;
    if (idx >= NBH * NN) return;
    const int bh = idx / NN, n = idx % NN;
    const float* row = S + ((size_t)bh * NP256 + n) * NP256;
    float l[4], mx = -1e30f;
#pragma unroll
    for (int j = 0; j < 4; j++) {
        int m = lane + j * 64;
        l[j] = (m < NN) ? row[m] : -1e30f;
        mx = fmaxf(mx, l[j]);
    }
    for (int off = 32; off > 0; off >>= 1) mx = fmaxf(mx, __shfl_xor(mx, off));
    float e[4], sum = 0.f;
#pragma unroll
    for (int j = 0; j < 4; j++) {
        int m = lane + j * 64;
        e[j] = (m < NN) ? expf(l[j] - mx) : 0.f;
        sum += e[j];
    }
    for (int off = 32; off > 0; off >>= 1) sum += __shfl_xor(sum, off);
    float inv = 1.f / sum;
    unsigned short* ar  = Ab  + ((size_t)bh * NP256 + n) * NP224;
    unsigned short* ar2 = A2b + ((size_t)bh * NP256 + n) * NP224;
#pragma unroll
    for (int j = 0; j < 4; j++) {
        int m = lane + j * 64;
        if (m < NP224) {
            float p = e[j] * inv;
            ar[m]  = f2b(p);
            ar2[m] = f2b(p * p);
        }
    }
}

// =============== ctx GEMM: [attn @ V | attn^2 @ CV] via MFMA ===============
__global__ __launch_bounds__(256) void ctx_gemm(
    const unsigned short* __restrict__ Ab, const unsigned short* __restrict__ A2b,
    const unsigned short* __restrict__ vT, const unsigned short* __restrict__ cvT,
    unsigned short* __restrict__ ctxm, unsigned short* __restrict__ ctxc)
{
    __shared__ unsigned short lA1[128 * 32];
    __shared__ unsigned short lA2[128 * 32];
    __shared__ unsigned short lB[128 * 32];
    const int tid = threadIdx.x, lane = tid & 63, wave = tid >> 6;
    const int wm = wave >> 1, wn = wave & 1;
    const int bh = blockIdx.y;
    const int b = bh / HH, h = bh % HH;
    const int m0 = blockIdx.x * 128;
    const int srow = lane >> 2, skoff = (lane & 3) * 8;
    const int fr = lane & 15, fk = (lane >> 4) * 8;

    f32x4 acc[4][4];
#pragma unroll
    for (int i = 0; i < 4; i++)
#pragma unroll
        for (int j = 0; j < 4; j++) acc[i][j] = (f32x4){0.f, 0.f, 0.f, 0.f};

    for (int k0 = 0; k0 < NP224; k0 += 32) {
#pragma unroll
        for (int i = 0; i < 2; i++) {
            int chunk = wave * 2 + i;
            int row = chunk * 16 + srow;
            size_t aoff = ((size_t)bh * NP256 + m0 + row) * NP224 + k0 + skoff;
            GLD(Ab + aoff,  lA1 + chunk * 512);
            GLD(A2b + aoff, lA2 + chunk * 512);
            const unsigned short* bsrc = (chunk < 4)
                ? (vT  + ((size_t)bh * 64 + row) * NP224)
                : (cvT + ((size_t)bh * 64 + row - 64) * NP224);
            GLD(bsrc + k0 + skoff, lB + chunk * 512);
        }
        __syncthreads();
        const unsigned short* asrc = wn ? lA2 : lA1;
        bf16x8 a[4], bfr[4];
#pragma unroll
        for (int t = 0; t < 4; t++) {
            a[t]   = *(const bf16x8*)(asrc + (wm * 64 + t * 16 + fr) * 32 + fk);
            bfr[t] = *(const bf16x8*)(lB   + (wn * 64 + t * 16 + fr) * 32 + fk);
        }
#pragma unroll
        for (int i = 0; i < 4; i++)
#pragma unroll
            for (int j = 0; j < 4; j++)
                acc[i][j] = __builtin_amdgcn_mfma_f32_16x16x32_bf16(a[i], bfr[j], acc[i][j], 0, 0, 0);
        __syncthreads();
    }

    const int lr = (lane >> 4) * 4;
    const int lc = lane & 15;
    unsigned short* dst = wn ? ctxc : ctxm;
#pragma unroll
    for (int i = 0; i < 4; i++) {
#pragma unroll
        for (int j = 0; j < 4; j++) {
            int dcol = j * 16 + lc;
#pragma unroll
            for (int r = 0; r < 4; r++) {
                int n = m0 + wm * 64 + i * 16 + lr + r;
                if (n >= NN) continue;
                dst[((size_t)(b * NN + n)) * EE + h * DD + dcol] = f2b(acc[i][j][r]);
            }
        }
    }
}

// =============== fp32 GEMM (head only) ===============
__global__ __launch_bounds__(256) void gemm_kernel(
    const float* __restrict__ A, const float* __restrict__ W,
    const float* __restrict__ bias, float* __restrict__ C,
    int M, int Nc, int K)
{
    __shared__ float As[16][64];
    __shared__ float Bs[16][64];
    const int tid = threadIdx.x;
    const int tm = tid >> 4;
    const int tn = tid & 15;
    const int m0 = blockIdx.y * 64;
    const int n0 = blockIdx.x * 64;
    float acc[4][4] = {};
    for (int k0 = 0; k0 < K; k0 += 16) {
#pragma unroll
        for (int i = 0; i < 4; i++) {
            int idx = tid + i * 256;
            int r = idx >> 4;
            int c = idx & 15;
            int gm = m0 + r;
            As[c][r] = (gm < M) ? A[(size_t)gm * K + k0 + c] : 0.f;
            int gn = n0 + r;
            Bs[c][r] = (gn < Nc) ? W[(size_t)gn * K + k0 + c] : 0.f;
        }
        __syncthreads();
#pragma unroll
        for (int kk = 0; kk < 16; kk++) {
            float a[4], b[4];
#pragma unroll
            for (int i = 0; i < 4; i++) a[i] = As[kk][tm * 4 + i];
#pragma unroll
            for (int j = 0; j < 4; j++) b[j] = Bs[kk][tn * 4 + j];
#pragma unroll
            for (int i = 0; i < 4; i++)
#pragma unroll
                for (int j = 0; j < 4; j++)
                    acc[i][j] += a[i] * b[j];
        }
        __syncthreads();
    }
#pragma unroll
    for (int i = 0; i < 4; i++) {
        int gm = m0 + tm * 4 + i;
        if (gm >= M) continue;
#pragma unroll
        for (int j = 0; j < 4; j++) {
            int gn = n0 + tn * 4 + j;
            if (gn >= Nc) continue;
            C[(size_t)gm * Nc + gn] = acc[i][j] + (bias ? bias[gn] : 0.f);
        }
    }
}

// =============== fp32 -> bf16 conversion ===============
__global__ __launch_bounds__(256) void cvt_kernel(
    const float* __restrict__ src, unsigned short* __restrict__ dst, int n)
{
    int i = (blockIdx.x * 256 + threadIdx.x) * 4;
    if (i >= n) return;
    float4 f = *(const float4*)(src + i);
    ushort4 u;
    u.x = f2b(f.x); u.y = f2b(f.y); u.z = f2b(f.z); u.w = f2b(f.w);
    *(ushort4*)(dst + i) = u;
}

#define W_QKV   0
#define W_PROJ  1769472
#define W_CPROJ 2359296
#define W_FC1   2949120
#define W_FC2   5308416
#define W_TOTAL 7667712

__global__ __launch_bounds__(256) void cvt_layer_kernel(
    const float* __restrict__ qkvw, const float* __restrict__ pw,
    const float* __restrict__ cpw, const float* __restrict__ f1,
    const float* __restrict__ f2, unsigned short* __restrict__ dst)
{
    int i = (blockIdx.x * 256 + threadIdx.x) * 4;
    if (i >= W_TOTAL) return;
    const float* s; int off;
    if (i < W_PROJ)        { s = qkvw; off = W_QKV; }
    else if (i < W_CPROJ)  { s = pw;   off = W_PROJ; }
    else if (i < W_FC1)    { s = cpw;  off = W_CPROJ; }
    else if (i < W_FC2)    { s = f1;   off = W_FC1; }
    else                   { s = f2;   off = W_FC2; }
    float4 f = *(const float4*)(s + (i - off));
    ushort4 u;
    u.x = f2b(f.x); u.y = f2b(f.y); u.z = f2b(f.z); u.w = f2b(f.w);
    *(ushort4*)(dst + i) = u;
}

// =============== im2col (bf16 out) ===============
__global__ __launch_bounds__(256) void im2col_kernel(
    const float* __restrict__ x, unsigned short* __restrict__ col)
{
    int idx = blockIdx.x * 256 + threadIdx.x;
    if (idx >= PROWS * EE) return;
    int c = idx % EE;
    int r = idx / EE;
    int b = r / NPATCH;
    int p = r % NPATCH;
    int ph = p / 14, pw = p % 14;
    int ch = c >> 8;
    int rem = c & 255;
    int i = rem >> 4, j = rem & 15;
    col[idx] = f2b(x[(((size_t)b * 3 + ch) * 224 + (ph * 16 + i)) * 224 + (pw * 16 + j)]);
}

// =============== assemble tokens ===============
__global__ __launch_bounds__(256) void assemble_kernel(
    const float* __restrict__ tm, const float* __restrict__ tc,
    const float* __restrict__ cls, const float* __restrict__ ccls,
    float* __restrict__ xm, float* __restrict__ xc)
{
    int idx = blockIdx.x * 256 + threadIdx.x;
    if (idx >= NROWS * EE) return;
    int e = idx % EE;
    int r = idx / EE;
    int b = r / NN, n = r % NN;
    if (n == 0) {
        xm[idx] = cls[e];
        xc[idx] = ccls[e];
    } else {
        size_t s = ((size_t)(b * NPATCH + n - 1)) * EE + e;
        xm[idx] = tm[s];
        xc[idx] = tc[s];
    }
}

// =============== merged LayerNorm for both streams (fp32 in, bf16 out) ===============
__global__ __launch_bounds__(256) void ln2_kernel(
    const float* __restrict__ xm, const float* __restrict__ xc,
    unsigned short* __restrict__ y, const float* __restrict__ g,
    const float* __restrict__ bb)
{
    int row = blockIdx.x;
    int tid = threadIdx.x;
    const float* src;
    size_t orow;
    if (row < NROWS) { src = xm + (size_t)row * EE; orow = row; }
    else { src = xc + (size_t)(row - NROWS) * EE; orow = (size_t)(row - NROWS) + MPAD; }
    __shared__ float red[256];
    float v0 = src[tid], v1 = src[tid + 256], v2 = src[tid + 512];
    red[tid] = v0 + v1 + v2;
    __syncthreads();
    for (int s = 128; s > 0; s >>= 1) { if (tid < s) red[tid] += red[tid + s]; __syncthreads(); }
    float mu = red[0] * (1.f / 768.f);
    __syncthreads();
    float d0 = v0 - mu, d1 = v1 - mu, d2 = v2 - mu;
    red[tid] = d0 * d0 + d1 * d1 + d2 * d2;
    __syncthreads();
    for (int s = 128; s > 0; s >>= 1) { if (tid < s) red[tid] += red[tid + s]; __syncthreads(); }
    float rstd = rsqrtf(red[0] * (1.f / 768.f) + 1e-5f);
    unsigned short* yr = y + orow * EE;
    yr[tid]       = f2b(d0 * rstd * g[tid]       + bb[tid]);
    yr[tid + 256] = f2b(d1 * rstd * g[tid + 256] + bb[tid + 256]);
    yr[tid + 512] = f2b(d2 * rstd * g[tid + 512] + bb[tid + 512]);
}

// =============== concat qkv biases ===============
__global__ __launch_bounds__(256) void qkvbias_kernel(
    const float* __restrict__ qb, const float* __restrict__ vb,
    const float* __restrict__ cqb, const float* __restrict__ cvb,
    float* __restrict__ bm, float* __restrict__ bc)
{
    int j = blockIdx.x * 256 + threadIdx.x;
    if (j >= 3 * EE) return;
    float m, c;
    if (j < EE)        { m = qb[j];        c = cqb[j]; }
    else if (j < 2*EE) { m = 0.f;          c = 0.f; }
    else               { m = vb[j - 2*EE]; c = cvb[j - 2*EE]; }
    bm[j] = m;
    bc[j] = c;
}

// =============== mean-pool + LN (fp32) ===============
__global__ __launch_bounds__(256) void pool_ln_kernel(
    const float* __restrict__ xm, float* __restrict__ out,
    const float* __restrict__ g, const float* __restrict__ bb)
{
    int b = blockIdx.x;
    int tid = threadIdx.x;
    __shared__ float red[256];
    float p[3];
#pragma unroll
    for (int i = 0; i < 3; i++) {
        int e = tid + i * 256;
        float s = 0.f;
        for (int n = 1; n < NN; n++) s += xm[((size_t)(b * NN + n)) * EE + e];
        p[i] = s * (1.f / 196.f);
    }
    red[tid] = p[0] + p[1] + p[2];
    __syncthreads();
    for (int s = 128; s > 0; s >>= 1) { if (tid < s) red[tid] += red[tid + s]; __syncthreads(); }
    float mu = red[0] * (1.f / 768.f);
    __syncthreads();
    float d0 = p[0] - mu, d1 = p[1] - mu, d2 = p[2] - mu;
    red[tid] = d0 * d0 + d1 * d1 + d2 * d2;
    __syncthreads();
    for (int s = 128; s > 0; s >>= 1) { if (tid < s) red[tid] += red[tid + s]; __syncthreads(); }
    float rstd = rsqrtf(red[0] * (1.f / 768.f) + 1e-5f);
    out[(size_t)b * EE + tid]       = d0 * rstd * g[tid]       + bb[tid];
    out[(size_t)b * EE + tid + 256] = d1 * rstd * g[tid + 256] + bb[tid + 256];
    out[(size_t)b * EE + tid + 512] = d2 * rstd * g[tid + 512] + bb[tid + 512];
}

// =========================================================================
extern "C" void kernel_launch(void* const* d_in, const int* in_sizes, int n_in,
                              void* d_out, int out_size, void* d_ws, size_t ws_size,
                              hipStream_t stream)
{
    const float* x        = (const float*)d_in[0];
    const float* rpb      = (const float*)d_in[1];
    const float* patch_w  = (const float*)d_in[2];
    const float* patch_b  = (const float*)d_in[3];
    const float* cpatch_w = (const float*)d_in[4];
    const float* cpatch_b = (const float*)d_in[5];
    const float* cls_tok  = (const float*)d_in[6];
    const float* ccls_tok = (const float*)d_in[7];
    const float* norm1_g  = (const float*)d_in[8];
    const float* norm1_b  = (const float*)d_in[9];
    const float* qkv_w    = (const float*)d_in[10];
    const float* q_bias   = (const float*)d_in[11];
    const float* v_bias   = (const float*)d_in[12];
    const float* cq_bias  = (const float*)d_in[13];
    const float* cv_bias  = (const float*)d_in[14];
    const float* proj_w   = (const float*)d_in[15];
    const float* proj_b   = (const float*)d_in[16];
    const float* cproj_w  = (const float*)d_in[17];
    const float* cproj_b  = (const float*)d_in[18];
    const float* gamma1   = (const float*)d_in[19];
    const float* gamma2   = (const float*)d_in[20];
    const float* norm2_g  = (const float*)d_in[21];
    const float* norm2_b  = (const float*)d_in[22];
    const float* fc1_w    = (const float*)d_in[23];
    const float* fc1_b    = (const float*)d_in[24];
    const float* fc2_w    = (const float*)d_in[25];
    const float* fc2_b    = (const float*)d_in[26];
    const float* fcn_g    = (const float*)d_in[27];
    const float* fcn_b    = (const float*)d_in[28];
    const float* head_w   = (const float*)d_in[29];
    const float* head_b   = (const float*)d_in[30];
    float* out = (float*)d_out;

    // ---- workspace layout ----
    char* base = (char*)d_ws;
    size_t off = 0;
    auto alloc = [&](size_t bytes) {
        void* p = base + off;
        off = (off + bytes + 255) & ~(size_t)255;
        return p;
    };
    unsigned short* wbuf  = (unsigned short*)alloc((size_t)W_TOTAL * 2);
    unsigned short* pw_m  = (unsigned short*)alloc((size_t)589824 * 2);
    unsigned short* pw_c  = (unsigned short*)alloc((size_t)589824 * 2);
    float* xm   = (float*)alloc((size_t)MPAD * EE * 4);
    float* xc   = (float*)alloc((size_t)MPAD * EE * 4);
    unsigned short* xn2 = (unsigned short*)alloc((size_t)2 * MPAD * EE * 2);
    float* qkv  = (float*)alloc((size_t)MPAD * 3 * EE * 4);
    float* cqkv = (float*)alloc((size_t)MPAD * 3 * EE * 4);
    // union region: S (25.2 MB) and hbuf (20.4 MB) have disjoint lifetimes
    char*  un   = (char*)alloc((size_t)NBH * NP256 * NP256 * 4);
    float* S    = (float*)un;
    unsigned short* hbuf = (unsigned short*)un;   // [2*MPAD][MLPD]
    unsigned short* Aq  = (unsigned short*)alloc((size_t)NBH * NP256 * 128 * 2);
    unsigned short* Bk  = (unsigned short*)alloc((size_t)NBH * NP256 * 128 * 2);
    unsigned short* vT  = (unsigned short*)alloc((size_t)NBH * 64 * NP224 * 2);
    unsigned short* cvT = (unsigned short*)alloc((size_t)NBH * 64 * NP224 * 2);
    float* rsum = (float*)alloc((size_t)NBH * NP256 * 4);
    float* csum = (float*)alloc((size_t)NBH * NP256 * 4);
    unsigned short* ctx2 = (unsigned short*)alloc((size_t)2 * MPAD * EE * 2);
    unsigned short* colb = (unsigned short*)alloc((size_t)MPAD * EE * 2);
    float* biasq  = (float*)alloc(3 * EE * 4);
    float* biasc  = (float*)alloc(3 * EE * 4);
    float* pooled = (float*)alloc((size_t)BB * EE * 4);
    // split-K partial buffer: up to 2 halves x 4 splits x [MPAD][EE] fp32 (40.9 MB)
    float* pbuf = (float*)alloc((size_t)2 * 4 * MPAD * EE * 4);
    // aliases
    unsigned short* Ab  = (unsigned short*)qkv;
    unsigned short* A2b = (unsigned short*)cqkv;
    float* tm = qkv;
    float* tc = cqkv;
    unsigned short* ctxm = ctx2;
    unsigned short* ctxc = ctx2 + (size_t)MPAD * EE;

    dim3 t256(256);
    dim3 gridRed(MPAD * EE / 1024, 2);

    // ---- patch embed (split-K S=3) ----
    cvt_kernel<<<dim3(589824 / 4 / 256), t256, 0, stream>>>(patch_w, pw_m, 589824);
    cvt_kernel<<<dim3(589824 / 4 / 256), t256, 0, stream>>>(cpatch_w, pw_c, 589824);
    im2col_kernel<<<dim3((PROWS * EE + 255) / 256), t256, 0, stream>>>(x, colb);
    mfma_gemm2_sk<<<dim3(EE / 128, 2 * HTILES, 3), t256, 0, stream>>>(
        colb, colb, pw_m, pw_c, EE, 256, EE, 3, pbuf);
    sk_reduce_kernel<<<gridRed, t256, 0, stream>>>(
        pbuf, 3, EE, MODE_F32, patch_b, cpatch_b, nullptr, nullptr, nullptr, tm, tc);
    assemble_kernel<<<dim3((NROWS * EE + 255) / 256), t256, 0, stream>>>(
        tm, tc, cls_tok, ccls_tok, xm, xc);

    dim3 gridQKV(3 * EE / 128, 2 * HTILES);
    dim3 gridMLP(MLPD / 128, 2 * HTILES);
    dim3 gridPre(4, NBH);
    dim3 gridWass(2, 2, NBH);
    dim3 gridSm((NBH * NN + 3) / 4);
    dim3 gridCtx(2, NBH);
    dim3 gridCvtL((W_TOTAL / 4 + 255) / 256);
    dim3 gridLN(2 * NROWS);
    const unsigned short* xn2c = xn2 + (size_t)MPAD * EE;
    const unsigned short* hbufc = hbuf + (size_t)MPAD * MLPD;

    for (int l = 0; l < LL; l++) {
        cvt_layer_kernel<<<gridCvtL, t256, 0, stream>>>(
            qkv_w + (size_t)l * 3 * EE * EE, proj_w + (size_t)l * EE * EE,
            cproj_w + (size_t)l * EE * EE, fc1_w + (size_t)l * MLPD * EE,
            fc2_w + (size_t)l * EE * MLPD, wbuf);
        qkvbias_kernel<<<dim3(9), t256, 0, stream>>>(
            q_bias + l * EE, v_bias + l * EE, cq_bias + l * EE, cv_bias + l * EE,
            biasq, biasc);

        // norm1 (both streams) + qkv dual GEMM (468 wg: keep fused epilogue)
        ln2_kernel<<<gridLN, t256, 0, stream>>>(xm, xc, xn2, norm1_g + l * EE, norm1_b + l * EE);
        mfma_gemm2<<<gridQKV, t256, 0, stream>>>(
            xn2, xn2c, wbuf + W_QKV, wbuf + W_QKV, biasq, biasc, EE, 3 * EE,
            MODE_F32, MODE_ELU1F, nullptr, nullptr, nullptr, qkv, cqkv, nullptr, nullptr);

        // attention
        pre_kernel<<<gridPre, t256, 0, stream>>>(qkv, cqkv, Aq, Bk, rsum, csum, vT, cvT);
        wass_gemm<<<gridWass, t256, 0, stream>>>(Aq, Bk, rsum, csum, rpb, S);
        softmax_kernel<<<gridSm, t256, 0, stream>>>(S, Ab, A2b);
        ctx_gemm<<<gridCtx, t256, 0, stream>>>(Ab, A2b, vT, cvT, ctxm, ctxc);

        // proj dual (split-K S=3) + fused residual in reduce
        mfma_gemm2_sk<<<dim3(EE / 128, 2 * HTILES, 3), t256, 0, stream>>>(
            ctxm, ctxc, wbuf + W_PROJ, wbuf + W_CPROJ, EE, 256, EE, 3, pbuf);
        sk_reduce_kernel<<<gridRed, t256, 0, stream>>>(
            pbuf, 3, EE, MODE_RESF, proj_b + l * EE, cproj_b + l * EE,
            gamma1 + l * EE, xm, xc, xm, xc);

        // norm2 + MLP dual
        ln2_kernel<<<gridLN, t256, 0, stream>>>(xm, xc, xn2, norm2_g + l * EE, norm2_b + l * EE);
        mfma_gemm2<<<gridMLP, t256, 0, stream>>>(
            xn2, xn2c, wbuf + W_FC1, wbuf + W_FC1, fc1_b + l * MLPD, fc1_b + l * MLPD,
            EE, MLPD, MODE_GELUB, MODE_GELUB, nullptr, nullptr, nullptr,
            nullptr, nullptr, hbuf, hbuf + (size_t)MPAD * MLPD);
        // fc2 dual (split-K S=4: 624 wg vs 156) + fused residual in reduce
        mfma_gemm2_sk<<<dim3(EE / 128, 2 * HTILES, 4), t256, 0, stream>>>(
            hbuf, hbufc, wbuf + W_FC2, wbuf + W_FC2, MLPD, 768, EE, 4, pbuf);
        sk_reduce_kernel<<<gridRed, t256, 0, stream>>>(
            pbuf, 4, EE, MODE_RESF, fc2_b + l * EE, fc2_b + l * EE,
            gamma2 + l * EE, xm, xc, xm, xc);
    }

    // ---- head ----
    pool_ln_kernel<<<dim3(BB), t256, 0, stream>>>(xm, pooled, fcn_g, fcn_b);
    {
        dim3 grid((NCLS + 63) / 64, (BB + 63) / 64);
        gemm_kernel<<<grid, t256, 0, stream>>>(pooled, head_w, head_b, out, BB, NCLS, EE);
    }
}

// Round 2
// 2880.473 us; speedup vs baseline: 1.5381x; 1.1187x over previous
//
#include <hip/hip_runtime.h>
#include <hip/hip_bf16.h>
#include <math.h>

#define BB 8
#define EE 768
#define HH 12
#define LL 12
#define DD 64
#define MLPD 3072
#define NN 197
#define NPATCH 196
#define NCLS 1000
#define NROWS (BB*NN)        // 1576
#define PROWS (BB*NPATCH)    // 1568
#define MPAD 1664            // 13 * 128
#define HTILES 13            // MPAD/128
#define NBH (BB*HH)          // 96
#define NP224 224
#define NP256 256
#define SCALE 0.125f

#define MODE_F32   0
#define MODE_ELU1F 1
#define MODE_GELUB 2
#define MODE_RESF  3

typedef __attribute__((ext_vector_type(8))) short bf16x8;
typedef __attribute__((ext_vector_type(4))) float f32x4;

__device__ __forceinline__ unsigned short f2b(float f) {
    union { __hip_bfloat16 h; unsigned short u; } x;
    x.h = __float2bfloat16(f);
    return x.u;
}

__device__ __forceinline__ float b2f(unsigned short u) {
    union { unsigned int i; float f; } x;
    x.i = ((unsigned int)u) << 16;
    return x.f;
}

#define GLD(gptr, lptr) __builtin_amdgcn_global_load_lds( \
    (const __attribute__((address_space(1))) unsigned int*)(gptr), \
    (__attribute__((address_space(3))) unsigned int*)(lptr), 16, 0, 0)

// =============== dual-half MFMA bf16 GEMM ===============
// blockIdx.y in [0,26): half = y>=13 selects {A,W,bias,mode,resid,out} set.
__global__ __launch_bounds__(256) void mfma_gemm2(
    const unsigned short* __restrict__ A0, const unsigned short* __restrict__ A1,
    const unsigned short* __restrict__ W0, const unsigned short* __restrict__ W1,
    const float* __restrict__ bias0, const float* __restrict__ bias1,
    int K, int Nc, int mode0, int mode1,
    const float* __restrict__ gamma,
    const float* __restrict__ resid0, const float* __restrict__ resid1,
    float* __restrict__ Cf0, float* __restrict__ Cf1,
    unsigned short* __restrict__ Cb0, unsigned short* __restrict__ Cb1)
{
    __shared__ unsigned short lA[128 * 32];
    __shared__ unsigned short lB[128 * 32];
    const int tid  = threadIdx.x;
    const int lane = tid & 63;
    const int wave = tid >> 6;
    const int wm = wave >> 1, wn = wave & 1;
    const int half = blockIdx.y >= HTILES;
    const int mout0 = (blockIdx.y - (half ? HTILES : 0)) * 128;
    const int n0 = blockIdx.x * 128;
    const unsigned short* A = half ? A1 : A0;
    const unsigned short* W = half ? W1 : W0;
    const float* bias = half ? bias1 : bias0;
    const float* resid = half ? resid1 : resid0;
    float* Cf = half ? Cf1 : Cf0;
    unsigned short* Cb = half ? Cb1 : Cb0;
    const int mode = half ? mode1 : mode0;

    const int srow  = lane >> 2;
    const int skoff = (lane & 3) * 8;
    const int fr = lane & 15;
    const int fk = (lane >> 4) * 8;

    f32x4 acc[4][4];
#pragma unroll
    for (int i = 0; i < 4; i++)
#pragma unroll
        for (int j = 0; j < 4; j++) acc[i][j] = (f32x4){0.f, 0.f, 0.f, 0.f};

    for (int k0 = 0; k0 < K; k0 += 32) {
#pragma unroll
        for (int i = 0; i < 2; i++) {
            int chunk = wave * 2 + i;
            int row = chunk * 16 + srow;
            GLD(A + (size_t)(mout0 + row) * K + k0 + skoff, lA + chunk * 512);
            GLD(W + (size_t)(n0 + row) * K + k0 + skoff, lB + chunk * 512);
        }
        __syncthreads();
        bf16x8 a[4], b[4];
#pragma unroll
        for (int t = 0; t < 4; t++) {
            a[t] = *(const bf16x8*)(lA + (wm * 64 + t * 16 + fr) * 32 + fk);
            b[t] = *(const bf16x8*)(lB + (wn * 64 + t * 16 + fr) * 32 + fk);
        }
#pragma unroll
        for (int i = 0; i < 4; i++)
#pragma unroll
            for (int j = 0; j < 4; j++)
                acc[i][j] = __builtin_amdgcn_mfma_f32_16x16x32_bf16(a[i], b[j], acc[i][j], 0, 0, 0);
        __syncthreads();
    }

    const int crow0 = mout0 + wm * 64;
    const int ccol0 = n0 + wn * 64;
    const int lr = (lane >> 4) * 4;
    const int lc = lane & 15;
#pragma unroll
    for (int i = 0; i < 4; i++) {
#pragma unroll
        for (int j = 0; j < 4; j++) {
            int col = ccol0 + j * 16 + lc;
            float bv = bias ? bias[col] : 0.f;
#pragma unroll
            for (int r = 0; r < 4; r++) {
                int row = crow0 + i * 16 + lr + r;
                float v = acc[i][j][r] + bv;
                size_t o = (size_t)row * Nc + col;
                if (mode == MODE_ELU1F) {
                    Cf[o] = (v > 0.f) ? (v + 1.f) : expf(v);
                } else if (mode == MODE_GELUB) {
                    v = 0.5f * v * (1.f + erff(v * 0.70710678118654752f));
                    Cb[o] = f2b(v);
                } else if (mode == MODE_RESF) {
                    Cf[o] = resid[o] + gamma[col] * v;
                } else {
                    Cf[o] = v;
                }
            }
        }
    }
}

// =============== split-K dual-half MFMA GEMM: fp32 partials, no epilogue ===============
// grid (Nc/128, 2*HTILES, S). Partial layout: P[(half*S + z)][MPAD][Nc].
__global__ __launch_bounds__(256) void mfma_gemm2_sk(
    const unsigned short* __restrict__ A0, const unsigned short* __restrict__ A1,
    const unsigned short* __restrict__ W0, const unsigned short* __restrict__ W1,
    int K, int Kc, int Nc, int S,
    float* __restrict__ P)
{
    __shared__ unsigned short lA[128 * 32];
    __shared__ unsigned short lB[128 * 32];
    const int tid  = threadIdx.x;
    const int lane = tid & 63;
    const int wave = tid >> 6;
    const int wm = wave >> 1, wn = wave & 1;
    const int half = blockIdx.y >= HTILES;
    const int mout0 = (blockIdx.y - (half ? HTILES : 0)) * 128;
    const int n0 = blockIdx.x * 128;
    const int z = blockIdx.z;
    const int kb = z * Kc;
    const unsigned short* A = half ? A1 : A0;
    const unsigned short* W = half ? W1 : W0;

    const int srow  = lane >> 2;
    const int skoff = (lane & 3) * 8;
    const int fr = lane & 15;
    const int fk = (lane >> 4) * 8;

    f32x4 acc[4][4];
#pragma unroll
    for (int i = 0; i < 4; i++)
#pragma unroll
        for (int j = 0; j < 4; j++) acc[i][j] = (f32x4){0.f, 0.f, 0.f, 0.f};

    for (int k0 = kb; k0 < kb + Kc; k0 += 32) {
#pragma unroll
        for (int i = 0; i < 2; i++) {
            int chunk = wave * 2 + i;
            int row = chunk * 16 + srow;
            GLD(A + (size_t)(mout0 + row) * K + k0 + skoff, lA + chunk * 512);
            GLD(W + (size_t)(n0 + row) * K + k0 + skoff, lB + chunk * 512);
        }
        __syncthreads();
        bf16x8 a[4], b[4];
#pragma unroll
        for (int t = 0; t < 4; t++) {
            a[t] = *(const bf16x8*)(lA + (wm * 64 + t * 16 + fr) * 32 + fk);
            b[t] = *(const bf16x8*)(lB + (wn * 64 + t * 16 + fr) * 32 + fk);
        }
#pragma unroll
        for (int i = 0; i < 4; i++)
#pragma unroll
            for (int j = 0; j < 4; j++)
                acc[i][j] = __builtin_amdgcn_mfma_f32_16x16x32_bf16(a[i], b[j], acc[i][j], 0, 0, 0);
        __syncthreads();
    }

    float* Pout = P + (size_t)(half * S + z) * MPAD * Nc;
    const int crow0 = mout0 + wm * 64;
    const int ccol0 = n0 + wn * 64;
    const int lr = (lane >> 4) * 4;
    const int lc = lane & 15;
#pragma unroll
    for (int i = 0; i < 4; i++) {
#pragma unroll
        for (int j = 0; j < 4; j++) {
            int col = ccol0 + j * 16 + lc;
#pragma unroll
            for (int r = 0; r < 4; r++) {
                int row = crow0 + i * 16 + lr + r;
                Pout[(size_t)row * Nc + col] = acc[i][j][r];
            }
        }
    }
}

// =============== split-K reduce + fused epilogue (F32 / RESF) ===============
__global__ __launch_bounds__(256) void sk_reduce_kernel(
    const float* __restrict__ P, int S, int Nc, int mode,
    const float* __restrict__ bias0, const float* __restrict__ bias1,
    const float* __restrict__ gamma,
    const float* __restrict__ resid0, const float* __restrict__ resid1,
    float* __restrict__ C0, float* __restrict__ C1)
{
    const size_t per = (size_t)MPAD * Nc;
    size_t gi = ((size_t)blockIdx.x * 256 + threadIdx.x) * 4;
    if (gi >= per) return;
    const int half = blockIdx.y;
    const float* p = P + (size_t)half * S * per + gi;
    float4 s = *(const float4*)p;
    for (int z = 1; z < S; z++) {
        float4 q = *(const float4*)(p + (size_t)z * per);
        s.x += q.x; s.y += q.y; s.z += q.z; s.w += q.w;
    }
    const int col = (int)(gi % (size_t)Nc);
    const float* bias = half ? bias1 : bias0;
    float4 bv = *(const float4*)(bias + col);
    s.x += bv.x; s.y += bv.y; s.z += bv.z; s.w += bv.w;
    float* C = half ? C1 : C0;
    if (mode == MODE_RESF) {
        const float* resid = half ? resid1 : resid0;
        float4 rv = *(const float4*)(resid + gi);
        float4 gv = *(const float4*)(gamma + col);
        s.x = rv.x + gv.x * s.x;
        s.y = rv.y + gv.y * s.y;
        s.z = rv.z + gv.z * s.z;
        s.w = rv.w + gv.w * s.w;
    }
    *(float4*)(C + gi) = s;
}

// =============== attention pre: operands + coalesced transpose ===============
__global__ __launch_bounds__(256) void pre_kernel(
    const float* __restrict__ qkv, const float* __restrict__ cqkv,
    unsigned short* __restrict__ Aq, unsigned short* __restrict__ Bk,
    float* __restrict__ rsum, float* __restrict__ csum,
    unsigned short* __restrict__ vT, unsigned short* __restrict__ cvT)
{
    const int t = blockIdx.x;
    const int bh = blockIdx.y;
    const int b = bh / HH, h = bh % HH;
    const int n0 = t * 64;
    const int lane = threadIdx.x & 63;
    const int w = threadIdx.x >> 6;
    __shared__ unsigned short vs[64][66];
    __shared__ unsigned short cvs[64][66];

    for (int p = 0; p < 16; p++) {
        int nl = p * 4 + w;
        int n = n0 + nl;
        int d = lane;
        size_t arow = ((size_t)bh * NP256 + n) * 128;
        if (n < NN) {
            size_t basei = (size_t)(b * NN + n) * 3 * EE + h * DD + d;
            float q  = qkv[basei];
            float k  = qkv[basei + EE];
            float v  = qkv[basei + 2 * EE];
            float cq = cqkv[basei];
            float ck = cqkv[basei + EE];
            float cv = cqkv[basei + 2 * EE];
            float qs = q * SCALE;
            float sqq = sqrtf(fmaxf(cq, 1e-24f));
            float sqk = sqrtf(fmaxf(ck, 1e-24f));
            Aq[arow + d]      = f2b(qs);
            Aq[arow + 64 + d] = f2b(sqq);
            Bk[arow + d]      = f2b(k);
            Bk[arow + 64 + d] = f2b(sqk);
            vs[nl][d]  = f2b(v);
            cvs[nl][d] = f2b(cv);
            float r = qs * qs + cq;
            float c = k * k + ck;
            for (int off2 = 32; off2 > 0; off2 >>= 1) {
                r += __shfl_down(r, off2);
                c += __shfl_down(c, off2);
            }
            if (d == 0) { rsum[bh * NP256 + n] = r; csum[bh * NP256 + n] = c; }
        } else {
            ((unsigned int*)(Aq + arow))[d] = 0u;
            ((unsigned int*)(Bk + arow))[d] = 0u;
            vs[nl][d] = 0; cvs[nl][d] = 0;
            if (d == 0) { rsum[bh * NP256 + n] = 0.f; csum[bh * NP256 + n] = 0.f; }
        }
    }
    __syncthreads();
    for (int p = 0; p < 16; p++) {
        int dr = p * 4 + w;
        int n = n0 + lane;
        if (n < NP224) {
            vT [((size_t)bh * 64 + dr) * NP224 + n] = vs[lane][dr];
            cvT[((size_t)bh * 64 + dr) * NP224 + n] = cvs[lane][dr];
        }
    }
}

// =============== fused attention: wasserstein + sigmoid + rpb + softmax + PV ===============
// grid (NP256/64 = 4, NBH). Each wg: 64 query rows x full 256 key cols.
// Wave w owns rows [q0 + w*16, q0 + w*16 + 16): full rows live in one wave ->
// row softmax = 16-lane shfl_xor reduce, no cross-wave traffic, no S in HBM.
#define PADW 232   // 464 B rows: 16B-aligned, bank-spread
__global__ __launch_bounds__(256) void attn_fused(
    const unsigned short* __restrict__ Aq, const unsigned short* __restrict__ Bk,
    const float* __restrict__ rsum, const float* __restrict__ csum,
    const float* __restrict__ rpb,
    const unsigned short* __restrict__ vT, const unsigned short* __restrict__ cvT,
    unsigned short* __restrict__ ctxm, unsigned short* __restrict__ ctxc)
{
    __shared__ unsigned short lA[64 * 32];     // 4 KB
    __shared__ unsigned short lB[256 * 32];    // 16 KB
    __shared__ unsigned short lB2[128 * 32];   // 8 KB
    __shared__ unsigned short pL[64 * PADW];   // 29.7 KB
    const int tid = threadIdx.x, lane = tid & 63, w = tid >> 6;
    const int bh = blockIdx.y;
    const int b = bh / HH, h = bh % HH;
    const int q0 = blockIdx.x * 64;
    const int srow = lane >> 2, skoff = (lane & 3) * 8;
    const int fr = lane & 15, fk = (lane >> 4) * 8;
    const int lr4 = (lane >> 4) * 4;
    const unsigned short* A = Aq + (size_t)bh * NP256 * 128;
    const unsigned short* B = Bk + (size_t)bh * NP256 * 128;

    // ---- phase 1: S[64 x 256] = Aq @ Bk^T (K=128) ----
    f32x4 accS[16];
#pragma unroll
    for (int j = 0; j < 16; j++) accS[j] = (f32x4){0.f, 0.f, 0.f, 0.f};

    for (int k0 = 0; k0 < 128; k0 += 32) {
        GLD(A + (size_t)(q0 + w * 16 + srow) * 128 + k0 + skoff, lA + w * 512);
#pragma unroll
        for (int i = 0; i < 4; i++) {
            int chunk = w * 4 + i;
            GLD(B + (size_t)(chunk * 16 + srow) * 128 + k0 + skoff, lB + chunk * 512);
        }
        __syncthreads();
        bf16x8 a = *(const bf16x8*)(lA + (w * 16 + fr) * 32 + fk);
#pragma unroll
        for (int j = 0; j < 16; j++) {
            bf16x8 bb = *(const bf16x8*)(lB + (j * 16 + fr) * 32 + fk);
            accS[j] = __builtin_amdgcn_mfma_f32_16x16x32_bf16(a, bb, accS[j], 0, 0, 0);
        }
        __syncthreads();
    }

    // ---- epilogue + row softmax, fully in registers ----
    // lane holds rows (q0 + w*16 + lr4 + r), cols (j*16 + fr)
    float rs[4];
#pragma unroll
    for (int r = 0; r < 4; r++) rs[r] = rsum[bh * NP256 + q0 + w * 16 + lr4 + r];
    float cs[16];
#pragma unroll
    for (int j = 0; j < 16; j++) cs[j] = csum[bh * NP256 + j * 16 + fr];

#pragma unroll
    for (int r = 0; r < 4; r++) {
        int rowg = q0 + w * 16 + lr4 + r;
        float v[16];
#pragma unroll
        for (int j = 0; j < 16; j++) {
            int col = j * 16 + fr;
            float z = 2.f * accS[j][r] - rs[r] - cs[j] + 1e-24f;
            float s = 1.f / (1.f + expf(-z));
            float rp = (col < NN && rowg < NN) ? rpb[((size_t)h * NN + rowg) * NN + col] : 0.f;
            v[j] = (col < NN) ? (s + rp) : -1e30f;
        }
        float mx = -1e30f;
#pragma unroll
        for (int j = 0; j < 16; j++) mx = fmaxf(mx, v[j]);
        mx = fmaxf(mx, __shfl_xor(mx, 1));
        mx = fmaxf(mx, __shfl_xor(mx, 2));
        mx = fmaxf(mx, __shfl_xor(mx, 4));
        mx = fmaxf(mx, __shfl_xor(mx, 8));
        float sum = 0.f;
#pragma unroll
        for (int j = 0; j < 16; j++) { v[j] = expf(v[j] - mx); sum += v[j]; }
        sum += __shfl_xor(sum, 1);
        sum += __shfl_xor(sum, 2);
        sum += __shfl_xor(sum, 4);
        sum += __shfl_xor(sum, 8);
        float inv = 1.f / sum;
        int rowl = w * 16 + lr4 + r;
#pragma unroll
        for (int j = 0; j < 14; j++)   // cols 224..255 are exactly 0, never read
            pL[rowl * PADW + j * 16 + fr] = f2b(v[j] * inv);
    }

    // ---- phase 2: ctx = P @ V^T and P^2 @ CV^T (K=224) ----
    f32x4 acc2[2][4];
#pragma unroll
    for (int p = 0; p < 2; p++)
#pragma unroll
        for (int j = 0; j < 4; j++) acc2[p][j] = (f32x4){0.f, 0.f, 0.f, 0.f};

    for (int k0 = 0; k0 < NP224; k0 += 32) {
#pragma unroll
        for (int i = 0; i < 2; i++) {
            int chunk = w * 2 + i;
            const unsigned short* src = (chunk < 4)
                ? (vT  + ((size_t)bh * 64 + chunk * 16 + srow) * NP224)
                : (cvT + ((size_t)bh * 64 + (chunk - 4) * 16 + srow) * NP224);
            GLD(src + k0 + skoff, lB2 + chunk * 512);
        }
        __syncthreads();   // also drains our own pL ds_writes on first iter
        bf16x8 ap = *(const bf16x8*)(pL + (w * 16 + fr) * PADW + k0 + fk);
        bf16x8 ap2;
#pragma unroll
        for (int e = 0; e < 8; e++) {
            float pv = b2f((unsigned short)ap[e]);
            ap2[e] = (short)f2b(pv * pv);
        }
#pragma unroll
        for (int j = 0; j < 4; j++) {
            bf16x8 bv = *(const bf16x8*)(lB2 + (j * 16 + fr) * 32 + fk);
            bf16x8 bc = *(const bf16x8*)(lB2 + ((64 + j * 16) + fr) * 32 + fk);
            acc2[0][j] = __builtin_amdgcn_mfma_f32_16x16x32_bf16(ap,  bv, acc2[0][j], 0, 0, 0);
            acc2[1][j] = __builtin_amdgcn_mfma_f32_16x16x32_bf16(ap2, bc, acc2[1][j], 0, 0, 0);
        }
        __syncthreads();
    }

#pragma unroll
    for (int j = 0; j < 4; j++) {
        int d = j * 16 + fr;
#pragma unroll
        for (int r = 0; r < 4; r++) {
            int n = q0 + w * 16 + lr4 + r;
            if (n >= NN) continue;
            size_t o = ((size_t)(b * NN + n)) * EE + h * DD + d;
            ctxm[o] = f2b(acc2[0][j][r]);
            ctxc[o] = f2b(acc2[1][j][r]);
        }
    }
}

// =============== head: wave-per-class dot product ===============
// grid (250, 8): wave handles one (b, class); K=768 strided by 64 lanes.
__global__ __launch_bounds__(256) void head_kernel(
    const float* __restrict__ pooled, const float* __restrict__ W,
    const float* __restrict__ bias, float* __restrict__ out)
{
    const int wv = threadIdx.x >> 6, lane = threadIdx.x & 63;
    const int c = blockIdx.x * 4 + wv;
    const int b = blockIdx.y;
    if (c >= NCLS) return;
    const float* wr = W + (size_t)c * EE;
    const float* pr = pooled + (size_t)b * EE;
    float s = 0.f;
#pragma unroll
    for (int i = 0; i < 12; i++) s += pr[lane + i * 64] * wr[lane + i * 64];
    for (int off = 32; off > 0; off >>= 1) s += __shfl_down(s, off);
    if (lane == 0) out[(size_t)b * NCLS + c] = s + bias[c];
}

// =============== fp32 -> bf16 conversion ===============
__global__ __launch_bounds__(256) void cvt_kernel(
    const float* __restrict__ src, unsigned short* __restrict__ dst, int n)
{
    int i = (blockIdx.x * 256 + threadIdx.x) * 4;
    if (i >= n) return;
    float4 f = *(const float4*)(src + i);
    ushort4 u;
    u.x = f2b(f.x); u.y = f2b(f.y); u.z = f2b(f.z); u.w = f2b(f.w);
    *(ushort4*)(dst + i) = u;
}

#define W_QKV   0
#define W_PROJ  1769472
#define W_CPROJ 2359296
#define W_FC1   2949120
#define W_FC2   5308416
#define W_TOTAL 7667712

__global__ __launch_bounds__(256) void cvt_layer_kernel(
    const float* __restrict__ qkvw, const float* __restrict__ pw,
    const float* __restrict__ cpw, const float* __restrict__ f1,
    const float* __restrict__ f2, unsigned short* __restrict__ dst)
{
    int i = (blockIdx.x * 256 + threadIdx.x) * 4;
    if (i >= W_TOTAL) return;
    const float* s; int off;
    if (i < W_PROJ)        { s = qkvw; off = W_QKV; }
    else if (i < W_CPROJ)  { s = pw;   off = W_PROJ; }
    else if (i < W_FC1)    { s = cpw;  off = W_CPROJ; }
    else if (i < W_FC2)    { s = f1;   off = W_FC1; }
    else                   { s = f2;   off = W_FC2; }
    float4 f = *(const float4*)(s + (i - off));
    ushort4 u;
    u.x = f2b(f.x); u.y = f2b(f.y); u.z = f2b(f.z); u.w = f2b(f.w);
    *(ushort4*)(dst + i) = u;
}

// =============== im2col (bf16 out) ===============
__global__ __launch_bounds__(256) void im2col_kernel(
    const float* __restrict__ x, unsigned short* __restrict__ col)
{
    int idx = blockIdx.x * 256 + threadIdx.x;
    if (idx >= PROWS * EE) return;
    int c = idx % EE;
    int r = idx / EE;
    int b = r / NPATCH;
    int p = r % NPATCH;
    int ph = p / 14, pw = p % 14;
    int ch = c >> 8;
    int rem = c & 255;
    int i = rem >> 4, j = rem & 15;
    col[idx] = f2b(x[(((size_t)b * 3 + ch) * 224 + (ph * 16 + i)) * 224 + (pw * 16 + j)]);
}

// =============== assemble tokens ===============
__global__ __launch_bounds__(256) void assemble_kernel(
    const float* __restrict__ tm, const float* __restrict__ tc,
    const float* __restrict__ cls, const float* __restrict__ ccls,
    float* __restrict__ xm, float* __restrict__ xc)
{
    int idx = blockIdx.x * 256 + threadIdx.x;
    if (idx >= NROWS * EE) return;
    int e = idx % EE;
    int r = idx / EE;
    int b = r / NN, n = r % NN;
    if (n == 0) {
        xm[idx] = cls[e];
        xc[idx] = ccls[e];
    } else {
        size_t s = ((size_t)(b * NPATCH + n - 1)) * EE + e;
        xm[idx] = tm[s];
        xc[idx] = tc[s];
    }
}

// =============== merged LayerNorm for both streams (fp32 in, bf16 out) ===============
__global__ __launch_bounds__(256) void ln2_kernel(
    const float* __restrict__ xm, const float* __restrict__ xc,
    unsigned short* __restrict__ y, const float* __restrict__ g,
    const float* __restrict__ bb)
{
    int row = blockIdx.x;
    int tid = threadIdx.x;
    const float* src;
    size_t orow;
    if (row < NROWS) { src = xm + (size_t)row * EE; orow = row; }
    else { src = xc + (size_t)(row - NROWS) * EE; orow = (size_t)(row - NROWS) + MPAD; }
    __shared__ float red[256];
    float v0 = src[tid], v1 = src[tid + 256], v2 = src[tid + 512];
    red[tid] = v0 + v1 + v2;
    __syncthreads();
    for (int s = 128; s > 0; s >>= 1) { if (tid < s) red[tid] += red[tid + s]; __syncthreads(); }
    float mu = red[0] * (1.f / 768.f);
    __syncthreads();
    float d0 = v0 - mu, d1 = v1 - mu, d2 = v2 - mu;
    red[tid] = d0 * d0 + d1 * d1 + d2 * d2;
    __syncthreads();
    for (int s = 128; s > 0; s >>= 1) { if (tid < s) red[tid] += red[tid + s]; __syncthreads(); }
    float rstd = rsqrtf(red[0] * (1.f / 768.f) + 1e-5f);
    unsigned short* yr = y + orow * EE;
    yr[tid]       = f2b(d0 * rstd * g[tid]       + bb[tid]);
    yr[tid + 256] = f2b(d1 * rstd * g[tid + 256] + bb[tid + 256]);
    yr[tid + 512] = f2b(d2 * rstd * g[tid + 512] + bb[tid + 512]);
}

// =============== concat qkv biases ===============
__global__ __launch_bounds__(256) void qkvbias_kernel(
    const float* __restrict__ qb, const float* __restrict__ vb,
    const float* __restrict__ cqb, const float* __restrict__ cvb,
    float* __restrict__ bm, float* __restrict__ bc)
{
    int j = blockIdx.x * 256 + threadIdx.x;
    if (j >= 3 * EE) return;
    float m, c;
    if (j < EE)        { m = qb[j];        c = cqb[j]; }
    else if (j < 2*EE) { m = 0.f;          c = 0.f; }
    else               { m = vb[j - 2*EE]; c = cvb[j - 2*EE]; }
    bm[j] = m;
    bc[j] = c;
}

// =============== mean-pool + LN (fp32) ===============
__global__ __launch_bounds__(256) void pool_ln_kernel(
    const float* __restrict__ xm, float* __restrict__ out,
    const float* __restrict__ g, const float* __restrict__ bb)
{
    int b = blockIdx.x;
    int tid = threadIdx.x;
    __shared__ float red[256];
    float p[3];
#pragma unroll
    for (int i = 0; i < 3; i++) {
        int e = tid + i * 256;
        float s = 0.f;
        for (int n = 1; n < NN; n++) s += xm[((size_t)(b * NN + n)) * EE + e];
        p[i] = s * (1.f / 196.f);
    }
    red[tid] = p[0] + p[1] + p[2];
    __syncthreads();
    for (int s = 128; s > 0; s >>= 1) { if (tid < s) red[tid] += red[tid + s]; __syncthreads(); }
    float mu = red[0] * (1.f / 768.f);
    __syncthreads();
    float d0 = p[0] - mu, d1 = p[1] - mu, d2 = p[2] - mu;
    red[tid] = d0 * d0 + d1 * d1 + d2 * d2;
    __syncthreads();
    for (int s = 128; s > 0; s >>= 1) { if (tid < s) red[tid] += red[tid + s]; __syncthreads(); }
    float rstd = rsqrtf(red[0] * (1.f / 768.f) + 1e-5f);
    out[(size_t)b * EE + tid]       = d0 * rstd * g[tid]       + bb[tid];
    out[(size_t)b * EE + tid + 256] = d1 * rstd * g[tid + 256] + bb[tid + 256];
    out[(size_t)b * EE + tid + 512] = d2 * rstd * g[tid + 512] + bb[tid + 512];
}

// =========================================================================
extern "C" void kernel_launch(void* const* d_in, const int* in_sizes, int n_in,
                              void* d_out, int out_size, void* d_ws, size_t ws_size,
                              hipStream_t stream)
{
    const float* x        = (const float*)d_in[0];
    const float* rpb      = (const float*)d_in[1];
    const float* patch_w  = (const float*)d_in[2];
    const float* patch_b  = (const float*)d_in[3];
    const float* cpatch_w = (const float*)d_in[4];
    const float* cpatch_b = (const float*)d_in[5];
    const float* cls_tok  = (const float*)d_in[6];
    const float* ccls_tok = (const float*)d_in[7];
    const float* norm1_g  = (const float*)d_in[8];
    const float* norm1_b  = (const float*)d_in[9];
    const float* qkv_w    = (const float*)d_in[10];
    const float* q_bias   = (const float*)d_in[11];
    const float* v_bias   = (const float*)d_in[12];
    const float* cq_bias  = (const float*)d_in[13];
    const float* cv_bias  = (const float*)d_in[14];
    const float* proj_w   = (const float*)d_in[15];
    const float* proj_b   = (const float*)d_in[16];
    const float* cproj_w  = (const float*)d_in[17];
    const float* cproj_b  = (const float*)d_in[18];
    const float* gamma1   = (const float*)d_in[19];
    const float* gamma2   = (const float*)d_in[20];
    const float* norm2_g  = (const float*)d_in[21];
    const float* norm2_b  = (const float*)d_in[22];
    const float* fc1_w    = (const float*)d_in[23];
    const float* fc1_b    = (const float*)d_in[24];
    const float* fc2_w    = (const float*)d_in[25];
    const float* fc2_b    = (const float*)d_in[26];
    const float* fcn_g    = (const float*)d_in[27];
    const float* fcn_b    = (const float*)d_in[28];
    const float* head_w   = (const float*)d_in[29];
    const float* head_b   = (const float*)d_in[30];
    float* out = (float*)d_out;

    // ---- workspace layout ----
    char* base = (char*)d_ws;
    size_t off = 0;
    auto alloc = [&](size_t bytes) {
        void* p = base + off;
        off = (off + bytes + 255) & ~(size_t)255;
        return p;
    };
    unsigned short* wbuf  = (unsigned short*)alloc((size_t)W_TOTAL * 2);
    unsigned short* pw_m  = (unsigned short*)alloc((size_t)589824 * 2);
    unsigned short* pw_c  = (unsigned short*)alloc((size_t)589824 * 2);
    float* xm   = (float*)alloc((size_t)MPAD * EE * 4);
    float* xc   = (float*)alloc((size_t)MPAD * EE * 4);
    unsigned short* xn2 = (unsigned short*)alloc((size_t)2 * MPAD * EE * 2);
    float* qkv  = (float*)alloc((size_t)MPAD * 3 * EE * 4);
    float* cqkv = (float*)alloc((size_t)MPAD * 3 * EE * 4);
    // hbuf: MLP hidden [2*MPAD][MLPD] bf16
    unsigned short* hbuf = (unsigned short*)alloc((size_t)2 * MPAD * MLPD * 2);
    unsigned short* Aq  = (unsigned short*)alloc((size_t)NBH * NP256 * 128 * 2);
    unsigned short* Bk  = (unsigned short*)alloc((size_t)NBH * NP256 * 128 * 2);
    unsigned short* vT  = (unsigned short*)alloc((size_t)NBH * 64 * NP224 * 2);
    unsigned short* cvT = (unsigned short*)alloc((size_t)NBH * 64 * NP224 * 2);
    float* rsum = (float*)alloc((size_t)NBH * NP256 * 4);
    float* csum = (float*)alloc((size_t)NBH * NP256 * 4);
    unsigned short* ctx2 = (unsigned short*)alloc((size_t)2 * MPAD * EE * 2);
    unsigned short* colb = (unsigned short*)alloc((size_t)MPAD * EE * 2);
    float* biasq  = (float*)alloc(3 * EE * 4);
    float* biasc  = (float*)alloc(3 * EE * 4);
    float* pooled = (float*)alloc((size_t)BB * EE * 4);
    // split-K partial buffer: up to 2 halves x 4 splits x [MPAD][EE] fp32
    float* pbuf = (float*)alloc((size_t)2 * 4 * MPAD * EE * 4);
    // aliases
    float* tm = qkv;
    float* tc = cqkv;
    unsigned short* ctxm = ctx2;
    unsigned short* ctxc = ctx2 + (size_t)MPAD * EE;

    dim3 t256(256);
    dim3 gridRed(MPAD * EE / 1024, 2);

    // ---- patch embed (split-K S=3) ----
    cvt_kernel<<<dim3(589824 / 4 / 256), t256, 0, stream>>>(patch_w, pw_m, 589824);
    cvt_kernel<<<dim3(589824 / 4 / 256), t256, 0, stream>>>(cpatch_w, pw_c, 589824);
    im2col_kernel<<<dim3((PROWS * EE + 255) / 256), t256, 0, stream>>>(x, colb);
    mfma_gemm2_sk<<<dim3(EE / 128, 2 * HTILES, 3), t256, 0, stream>>>(
        colb, colb, pw_m, pw_c, EE, 256, EE, 3, pbuf);
    sk_reduce_kernel<<<gridRed, t256, 0, stream>>>(
        pbuf, 3, EE, MODE_F32, patch_b, cpatch_b, nullptr, nullptr, nullptr, tm, tc);
    assemble_kernel<<<dim3((NROWS * EE + 255) / 256), t256, 0, stream>>>(
        tm, tc, cls_tok, ccls_tok, xm, xc);

    dim3 gridQKV(3 * EE / 128, 2 * HTILES);
    dim3 gridMLP(MLPD / 128, 2 * HTILES);
    dim3 gridPre(4, NBH);
    dim3 gridAttn(4, NBH);
    dim3 gridCvtL((W_TOTAL / 4 + 255) / 256);
    dim3 gridLN(2 * NROWS);
    const unsigned short* xn2c = xn2 + (size_t)MPAD * EE;
    const unsigned short* hbufc = hbuf + (size_t)MPAD * MLPD;

    for (int l = 0; l < LL; l++) {
        cvt_layer_kernel<<<gridCvtL, t256, 0, stream>>>(
            qkv_w + (size_t)l * 3 * EE * EE, proj_w + (size_t)l * EE * EE,
            cproj_w + (size_t)l * EE * EE, fc1_w + (size_t)l * MLPD * EE,
            fc2_w + (size_t)l * EE * MLPD, wbuf);
        qkvbias_kernel<<<dim3(9), t256, 0, stream>>>(
            q_bias + l * EE, v_bias + l * EE, cq_bias + l * EE, cv_bias + l * EE,
            biasq, biasc);

        // norm1 (both streams) + qkv dual GEMM (468 wg: keep fused epilogue)
        ln2_kernel<<<gridLN, t256, 0, stream>>>(xm, xc, xn2, norm1_g + l * EE, norm1_b + l * EE);
        mfma_gemm2<<<gridQKV, t256, 0, stream>>>(
            xn2, xn2c, wbuf + W_QKV, wbuf + W_QKV, biasq, biasc, EE, 3 * EE,
            MODE_F32, MODE_ELU1F, nullptr, nullptr, nullptr, qkv, cqkv, nullptr, nullptr);

        // attention: pre + fully fused wass/softmax/PV
        pre_kernel<<<gridPre, t256, 0, stream>>>(qkv, cqkv, Aq, Bk, rsum, csum, vT, cvT);
        attn_fused<<<gridAttn, t256, 0, stream>>>(Aq, Bk, rsum, csum, rpb, vT, cvT, ctxm, ctxc);

        // proj dual (split-K S=3) + fused residual in reduce
        mfma_gemm2_sk<<<dim3(EE / 128, 2 * HTILES, 3), t256, 0, stream>>>(
            ctxm, ctxc, wbuf + W_PROJ, wbuf + W_CPROJ, EE, 256, EE, 3, pbuf);
        sk_reduce_kernel<<<gridRed, t256, 0, stream>>>(
            pbuf, 3, EE, MODE_RESF, proj_b + l * EE, cproj_b + l * EE,
            gamma1 + l * EE, xm, xc, xm, xc);

        // norm2 + MLP dual
        ln2_kernel<<<gridLN, t256, 0, stream>>>(xm, xc, xn2, norm2_g + l * EE, norm2_b + l * EE);
        mfma_gemm2<<<gridMLP, t256, 0, stream>>>(
            xn2, xn2c, wbuf + W_FC1, wbuf + W_FC1, fc1_b + l * MLPD, fc1_b + l * MLPD,
            EE, MLPD, MODE_GELUB, MODE_GELUB, nullptr, nullptr, nullptr,
            nullptr, nullptr, hbuf, hbuf + (size_t)MPAD * MLPD);
        // fc2 dual (split-K S=4) + fused residual in reduce
        mfma_gemm2_sk<<<dim3(EE / 128, 2 * HTILES, 4), t256, 0, stream>>>(
            hbuf, hbufc, wbuf + W_FC2, wbuf + W_FC2, MLPD, 768, EE, 4, pbuf);
        sk_reduce_kernel<<<gridRed, t256, 0, stream>>>(
            pbuf, 4, EE, MODE_RESF, fc2_b + l * EE, fc2_b + l * EE,
            gamma2 + l * EE, xm, xc, xm, xc);
    }

    // ---- head ----
    pool_ln_kernel<<<dim3(BB), t256, 0, stream>>>(xm, pooled, fcn_g, fcn_b);
    head_kernel<<<dim3((NCLS + 3) / 4, BB), t256, 0, stream>>>(pooled, head_w, head_b, out);
}

// Round 3
// 2653.860 us; speedup vs baseline: 1.6694x; 1.0854x over previous
//
#include <hip/hip_runtime.h>
#include <hip/hip_bf16.h>
#include <math.h>

#define BB 8
#define EE 768
#define HH 12
#define LL 12
#define DD 64
#define MLPD 3072
#define NN 197
#define NPATCH 196
#define NCLS 1000
#define NROWS (BB*NN)        // 1576
#define PROWS (BB*NPATCH)    // 1568
#define MPAD 1664            // 13 * 128
#define HTILES 13            // MPAD/128
#define NBH (BB*HH)          // 96
#define NP224 224
#define NP256 256
#define SCALE 0.125f

#define MODE_F32   0
#define MODE_ELU1F 1
#define MODE_GELUB 2
#define MODE_RESF  3

typedef __attribute__((ext_vector_type(8))) short bf16x8;
typedef __attribute__((ext_vector_type(4))) float f32x4;

__device__ __forceinline__ unsigned short f2b(float f) {
    union { __hip_bfloat16 h; unsigned short u; } x;
    x.h = __float2bfloat16(f);
    return x.u;
}

__device__ __forceinline__ float b2f(unsigned short u) {
    union { unsigned int i; float f; } x;
    x.i = ((unsigned int)u) << 16;
    return x.f;
}

#define GLD(gptr, lptr) __builtin_amdgcn_global_load_lds( \
    (const __attribute__((address_space(1))) unsigned int*)(gptr), \
    (__attribute__((address_space(3))) unsigned int*)(lptr), 16, 0, 0)

// =============== dual-half MFMA bf16 GEMM (2-phase double-buffered) ===============
// blockIdx.y in [0,26): half = y>=13 selects {A,W,bias,mode,resid,out} set.
__global__ __launch_bounds__(256) void mfma_gemm2(
    const unsigned short* __restrict__ A0, const unsigned short* __restrict__ A1,
    const unsigned short* __restrict__ W0, const unsigned short* __restrict__ W1,
    const float* __restrict__ bias0, const float* __restrict__ bias1,
    int K, int Nc, int mode0, int mode1,
    const float* __restrict__ gamma,
    const float* __restrict__ resid0, const float* __restrict__ resid1,
    float* __restrict__ Cf0, float* __restrict__ Cf1,
    unsigned short* __restrict__ Cb0, unsigned short* __restrict__ Cb1)
{
    __shared__ unsigned short lA[2][128 * 32];
    __shared__ unsigned short lB[2][128 * 32];
    const int tid  = threadIdx.x;
    const int lane = tid & 63;
    const int wave = tid >> 6;
    const int wm = wave >> 1, wn = wave & 1;
    const int half = blockIdx.y >= HTILES;
    const int mout0 = (blockIdx.y - (half ? HTILES : 0)) * 128;
    const int n0 = blockIdx.x * 128;
    const unsigned short* A = half ? A1 : A0;
    const unsigned short* W = half ? W1 : W0;
    const float* bias = half ? bias1 : bias0;
    const float* resid = half ? resid1 : resid0;
    float* Cf = half ? Cf1 : Cf0;
    unsigned short* Cb = half ? Cb1 : Cb0;
    const int mode = half ? mode1 : mode0;

    const int srow  = lane >> 2;
    const int skoff = (lane & 3) * 8;
    const int fr = lane & 15;
    const int fk = (lane >> 4) * 8;

    auto stage = [&](int bufi, int k0) {
#pragma unroll
        for (int i = 0; i < 2; i++) {
            int chunk = wave * 2 + i;
            int row = chunk * 16 + srow;
            GLD(A + (size_t)(mout0 + row) * K + k0 + skoff, &lA[bufi][chunk * 512]);
            GLD(W + (size_t)(n0 + row) * K + k0 + skoff, &lB[bufi][chunk * 512]);
        }
    };

    f32x4 acc[4][4];
#pragma unroll
    for (int i = 0; i < 4; i++)
#pragma unroll
        for (int j = 0; j < 4; j++) acc[i][j] = (f32x4){0.f, 0.f, 0.f, 0.f};

    const int NT = K >> 5;
    stage(0, 0);
    __syncthreads();
    int cur = 0;
    for (int t = 0; t < NT; t++) {
        if (t + 1 < NT) stage(cur ^ 1, (t + 1) * 32);
        bf16x8 a[4], b[4];
#pragma unroll
        for (int q = 0; q < 4; q++) {
            a[q] = *(const bf16x8*)(&lA[cur][(wm * 64 + q * 16 + fr) * 32 + fk]);
            b[q] = *(const bf16x8*)(&lB[cur][(wn * 64 + q * 16 + fr) * 32 + fk]);
        }
#pragma unroll
        for (int i = 0; i < 4; i++)
#pragma unroll
            for (int j = 0; j < 4; j++)
                acc[i][j] = __builtin_amdgcn_mfma_f32_16x16x32_bf16(a[i], b[j], acc[i][j], 0, 0, 0);
        __syncthreads();
        cur ^= 1;
    }

    const int crow0 = mout0 + wm * 64;
    const int ccol0 = n0 + wn * 64;
    const int lr = (lane >> 4) * 4;
    const int lc = lane & 15;
#pragma unroll
    for (int i = 0; i < 4; i++) {
#pragma unroll
        for (int j = 0; j < 4; j++) {
            int col = ccol0 + j * 16 + lc;
            float bv = bias ? bias[col] : 0.f;
#pragma unroll
            for (int r = 0; r < 4; r++) {
                int row = crow0 + i * 16 + lr + r;
                float v = acc[i][j][r] + bv;
                size_t o = (size_t)row * Nc + col;
                if (mode == MODE_ELU1F) {
                    Cf[o] = (v > 0.f) ? (v + 1.f) : expf(v);
                } else if (mode == MODE_GELUB) {
                    v = 0.5f * v * (1.f + erff(v * 0.70710678118654752f));
                    Cb[o] = f2b(v);
                } else if (mode == MODE_RESF) {
                    Cf[o] = resid[o] + gamma[col] * v;
                } else {
                    Cf[o] = v;
                }
            }
        }
    }
}

// =============== split-K dual-half MFMA GEMM (2-phase dbuf): fp32 partials ===============
// grid (Nc/128, 2*HTILES, S). Partial layout: P[(half*S + z)][MPAD][Nc].
__global__ __launch_bounds__(256) void mfma_gemm2_sk(
    const unsigned short* __restrict__ A0, const unsigned short* __restrict__ A1,
    const unsigned short* __restrict__ W0, const unsigned short* __restrict__ W1,
    int K, int Kc, int Nc, int S,
    float* __restrict__ P)
{
    __shared__ unsigned short lA[2][128 * 32];
    __shared__ unsigned short lB[2][128 * 32];
    const int tid  = threadIdx.x;
    const int lane = tid & 63;
    const int wave = tid >> 6;
    const int wm = wave >> 1, wn = wave & 1;
    const int half = blockIdx.y >= HTILES;
    const int mout0 = (blockIdx.y - (half ? HTILES : 0)) * 128;
    const int n0 = blockIdx.x * 128;
    const int z = blockIdx.z;
    const int kb = z * Kc;
    const unsigned short* A = half ? A1 : A0;
    const unsigned short* W = half ? W1 : W0;

    const int srow  = lane >> 2;
    const int skoff = (lane & 3) * 8;
    const int fr = lane & 15;
    const int fk = (lane >> 4) * 8;

    auto stage = [&](int bufi, int k0) {
#pragma unroll
        for (int i = 0; i < 2; i++) {
            int chunk = wave * 2 + i;
            int row = chunk * 16 + srow;
            GLD(A + (size_t)(mout0 + row) * K + k0 + skoff, &lA[bufi][chunk * 512]);
            GLD(W + (size_t)(n0 + row) * K + k0 + skoff, &lB[bufi][chunk * 512]);
        }
    };

    f32x4 acc[4][4];
#pragma unroll
    for (int i = 0; i < 4; i++)
#pragma unroll
        for (int j = 0; j < 4; j++) acc[i][j] = (f32x4){0.f, 0.f, 0.f, 0.f};

    const int NT = Kc >> 5;
    stage(0, kb);
    __syncthreads();
    int cur = 0;
    for (int t = 0; t < NT; t++) {
        if (t + 1 < NT) stage(cur ^ 1, kb + (t + 1) * 32);
        bf16x8 a[4], b[4];
#pragma unroll
        for (int q = 0; q < 4; q++) {
            a[q] = *(const bf16x8*)(&lA[cur][(wm * 64 + q * 16 + fr) * 32 + fk]);
            b[q] = *(const bf16x8*)(&lB[cur][(wn * 64 + q * 16 + fr) * 32 + fk]);
        }
#pragma unroll
        for (int i = 0; i < 4; i++)
#pragma unroll
            for (int j = 0; j < 4; j++)
                acc[i][j] = __builtin_amdgcn_mfma_f32_16x16x32_bf16(a[i], b[j], acc[i][j], 0, 0, 0);
        __syncthreads();
        cur ^= 1;
    }

    float* Pout = P + (size_t)(half * S + z) * MPAD * Nc;
    const int crow0 = mout0 + wm * 64;
    const int ccol0 = n0 + wn * 64;
    const int lr = (lane >> 4) * 4;
    const int lc = lane & 15;
#pragma unroll
    for (int i = 0; i < 4; i++) {
#pragma unroll
        for (int j = 0; j < 4; j++) {
            int col = ccol0 + j * 16 + lc;
#pragma unroll
            for (int r = 0; r < 4; r++) {
                int row = crow0 + i * 16 + lr + r;
                Pout[(size_t)row * Nc + col] = acc[i][j][r];
            }
        }
    }
}

// =============== split-K reduce (elementwise, patch embed only) ===============
__global__ __launch_bounds__(256) void sk_reduce_kernel(
    const float* __restrict__ P, int S, int Nc,
    const float* __restrict__ bias0, const float* __restrict__ bias1,
    float* __restrict__ C0, float* __restrict__ C1)
{
    const size_t per = (size_t)MPAD * Nc;
    size_t gi = ((size_t)blockIdx.x * 256 + threadIdx.x) * 4;
    if (gi >= per) return;
    const int half = blockIdx.y;
    const float* p = P + (size_t)half * S * per + gi;
    float4 s = *(const float4*)p;
    for (int z = 1; z < S; z++) {
        float4 q = *(const float4*)(p + (size_t)z * per);
        s.x += q.x; s.y += q.y; s.z += q.z; s.w += q.w;
    }
    const int col = (int)(gi % (size_t)Nc);
    const float* bias = half ? bias1 : bias0;
    float4 bv = *(const float4*)(bias + col);
    s.x += bv.x; s.y += bv.y; s.z += bv.z; s.w += bv.w;
    float* C = half ? C1 : C0;
    *(float4*)(C + gi) = s;
}

// =============== split-K reduce + residual + fused LayerNorm ===============
// grid (MPAD, 2), 256 threads. One row per block:
//   C = resid + gamma * (sum_z P[z] + bias)   (fp32, residual stream)
//   Y = LN(C) * lnG + lnB                      (bf16, next GEMM input; skip if !Y)
__global__ __launch_bounds__(256) void sk_reduce_ln(
    const float* __restrict__ P, int S,
    const float* __restrict__ bias0, const float* __restrict__ bias1,
    const float* __restrict__ gamma,
    const float* __restrict__ resid0, const float* __restrict__ resid1,
    float* __restrict__ C0, float* __restrict__ C1,
    const float* __restrict__ lnG, const float* __restrict__ lnB,
    unsigned short* __restrict__ Y)
{
    const int row = blockIdx.x;
    const int half = blockIdx.y;
    const int tid = threadIdx.x;
    const size_t per = (size_t)MPAD * EE;
    const float* p = P + (size_t)half * S * per + (size_t)row * EE;
    const float* bias = half ? bias1 : bias0;
    const float* resid = half ? resid1 : resid0;
    float* C = half ? C1 : C0;
    float v[3];
#pragma unroll
    for (int i = 0; i < 3; i++) {
        int e = tid + i * 256;
        float s = p[e];
        for (int z = 1; z < S; z++) s += p[(size_t)z * per + e];
        v[i] = resid[(size_t)row * EE + e] + gamma[e] * (s + bias[e]);
        C[(size_t)row * EE + e] = v[i];
    }
    if (!Y) return;
    __shared__ float red[256];
    red[tid] = v[0] + v[1] + v[2];
    __syncthreads();
    for (int s2 = 128; s2 > 0; s2 >>= 1) { if (tid < s2) red[tid] += red[tid + s2]; __syncthreads(); }
    float mu = red[0] * (1.f / 768.f);
    __syncthreads();
    float d0 = v[0] - mu, d1 = v[1] - mu, d2 = v[2] - mu;
    red[tid] = d0 * d0 + d1 * d1 + d2 * d2;
    __syncthreads();
    for (int s2 = 128; s2 > 0; s2 >>= 1) { if (tid < s2) red[tid] += red[tid + s2]; __syncthreads(); }
    float rstd = rsqrtf(red[0] * (1.f / 768.f) + 1e-5f);
    unsigned short* yr = Y + ((size_t)half * MPAD + row) * EE;
    yr[tid]       = f2b(d0 * rstd * lnG[tid]       + lnB[tid]);
    yr[tid + 256] = f2b(d1 * rstd * lnG[tid + 256] + lnB[tid + 256]);
    yr[tid + 512] = f2b(d2 * rstd * lnG[tid + 512] + lnB[tid + 512]);
}

// =============== attention pre: operands + coalesced transpose ===============
__global__ __launch_bounds__(256) void pre_kernel(
    const float* __restrict__ qkv, const float* __restrict__ cqkv,
    unsigned short* __restrict__ Aq, unsigned short* __restrict__ Bk,
    float* __restrict__ rsum, float* __restrict__ csum,
    unsigned short* __restrict__ vT, unsigned short* __restrict__ cvT)
{
    const int t = blockIdx.x;
    const int bh = blockIdx.y;
    const int b = bh / HH, h = bh % HH;
    const int n0 = t * 64;
    const int lane = threadIdx.x & 63;
    const int w = threadIdx.x >> 6;
    __shared__ unsigned short vs[64][66];
    __shared__ unsigned short cvs[64][66];

    for (int p = 0; p < 16; p++) {
        int nl = p * 4 + w;
        int n = n0 + nl;
        int d = lane;
        size_t arow = ((size_t)bh * NP256 + n) * 128;
        if (n < NN) {
            size_t basei = (size_t)(b * NN + n) * 3 * EE + h * DD + d;
            float q  = qkv[basei];
            float k  = qkv[basei + EE];
            float v  = qkv[basei + 2 * EE];
            float cq = cqkv[basei];
            float ck = cqkv[basei + EE];
            float cv = cqkv[basei + 2 * EE];
            float qs = q * SCALE;
            float sqq = sqrtf(fmaxf(cq, 1e-24f));
            float sqk = sqrtf(fmaxf(ck, 1e-24f));
            Aq[arow + d]      = f2b(qs);
            Aq[arow + 64 + d] = f2b(sqq);
            Bk[arow + d]      = f2b(k);
            Bk[arow + 64 + d] = f2b(sqk);
            vs[nl][d]  = f2b(v);
            cvs[nl][d] = f2b(cv);
            float r = qs * qs + cq;
            float c = k * k + ck;
            for (int off2 = 32; off2 > 0; off2 >>= 1) {
                r += __shfl_down(r, off2);
                c += __shfl_down(c, off2);
            }
            if (d == 0) { rsum[bh * NP256 + n] = r; csum[bh * NP256 + n] = c; }
        } else {
            ((unsigned int*)(Aq + arow))[d] = 0u;
            ((unsigned int*)(Bk + arow))[d] = 0u;
            vs[nl][d] = 0; cvs[nl][d] = 0;
            if (d == 0) { rsum[bh * NP256 + n] = 0.f; csum[bh * NP256 + n] = 0.f; }
        }
    }
    __syncthreads();
    for (int p = 0; p < 16; p++) {
        int dr = p * 4 + w;
        int n = n0 + lane;
        if (n < NP224) {
            vT [((size_t)bh * 64 + dr) * NP224 + n] = vs[lane][dr];
            cvT[((size_t)bh * 64 + dr) * NP224 + n] = cvs[lane][dr];
        }
    }
}

// =============== fused attention: wasserstein + sigmoid + rpb + softmax + PV ===============
#define PADW 232   // 464 B rows: 16B-aligned, bank-spread
__global__ __launch_bounds__(256) void attn_fused(
    const unsigned short* __restrict__ Aq, const unsigned short* __restrict__ Bk,
    const float* __restrict__ rsum, const float* __restrict__ csum,
    const float* __restrict__ rpb,
    const unsigned short* __restrict__ vT, const unsigned short* __restrict__ cvT,
    unsigned short* __restrict__ ctxm, unsigned short* __restrict__ ctxc)
{
    __shared__ unsigned short lA[64 * 32];     // 4 KB
    __shared__ unsigned short lB[256 * 32];    // 16 KB
    __shared__ unsigned short lB2[128 * 32];   // 8 KB
    __shared__ unsigned short pL[64 * PADW];   // 29.7 KB
    const int tid = threadIdx.x, lane = tid & 63, w = tid >> 6;
    const int bh = blockIdx.y;
    const int b = bh / HH, h = bh % HH;
    const int q0 = blockIdx.x * 64;
    const int srow = lane >> 2, skoff = (lane & 3) * 8;
    const int fr = lane & 15, fk = (lane >> 4) * 8;
    const int lr4 = (lane >> 4) * 4;
    const unsigned short* A = Aq + (size_t)bh * NP256 * 128;
    const unsigned short* B = Bk + (size_t)bh * NP256 * 128;

    // ---- phase 1: S[64 x 256] = Aq @ Bk^T (K=128) ----
    f32x4 accS[16];
#pragma unroll
    for (int j = 0; j < 16; j++) accS[j] = (f32x4){0.f, 0.f, 0.f, 0.f};

    for (int k0 = 0; k0 < 128; k0 += 32) {
        GLD(A + (size_t)(q0 + w * 16 + srow) * 128 + k0 + skoff, lA + w * 512);
#pragma unroll
        for (int i = 0; i < 4; i++) {
            int chunk = w * 4 + i;
            GLD(B + (size_t)(chunk * 16 + srow) * 128 + k0 + skoff, lB + chunk * 512);
        }
        __syncthreads();
        bf16x8 a = *(const bf16x8*)(lA + (w * 16 + fr) * 32 + fk);
#pragma unroll
        for (int j = 0; j < 16; j++) {
            bf16x8 bb = *(const bf16x8*)(lB + (j * 16 + fr) * 32 + fk);
            accS[j] = __builtin_amdgcn_mfma_f32_16x16x32_bf16(a, bb, accS[j], 0, 0, 0);
        }
        __syncthreads();
    }

    // ---- epilogue + row softmax, fully in registers ----
    float rs[4];
#pragma unroll
    for (int r = 0; r < 4; r++) rs[r] = rsum[bh * NP256 + q0 + w * 16 + lr4 + r];
    float cs[16];
#pragma unroll
    for (int j = 0; j < 16; j++) cs[j] = csum[bh * NP256 + j * 16 + fr];

#pragma unroll
    for (int r = 0; r < 4; r++) {
        int rowg = q0 + w * 16 + lr4 + r;
        float v[16];
#pragma unroll
        for (int j = 0; j < 16; j++) {
            int col = j * 16 + fr;
            float z = 2.f * accS[j][r] - rs[r] - cs[j] + 1e-24f;
            float s = 1.f / (1.f + expf(-z));
            float rp = (col < NN && rowg < NN) ? rpb[((size_t)h * NN + rowg) * NN + col] : 0.f;
            v[j] = (col < NN) ? (s + rp) : -1e30f;
        }
        float mx = -1e30f;
#pragma unroll
        for (int j = 0; j < 16; j++) mx = fmaxf(mx, v[j]);
        mx = fmaxf(mx, __shfl_xor(mx, 1));
        mx = fmaxf(mx, __shfl_xor(mx, 2));
        mx = fmaxf(mx, __shfl_xor(mx, 4));
        mx = fmaxf(mx, __shfl_xor(mx, 8));
        float sum = 0.f;
#pragma unroll
        for (int j = 0; j < 16; j++) { v[j] = expf(v[j] - mx); sum += v[j]; }
        sum += __shfl_xor(sum, 1);
        sum += __shfl_xor(sum, 2);
        sum += __shfl_xor(sum, 4);
        sum += __shfl_xor(sum, 8);
        float inv = 1.f / sum;
        int rowl = w * 16 + lr4 + r;
#pragma unroll
        for (int j = 0; j < 14; j++)   // cols 224..255 are exactly 0, never read
            pL[rowl * PADW + j * 16 + fr] = f2b(v[j] * inv);
    }

    // ---- phase 2: ctx = P @ V^T and P^2 @ CV^T (K=224) ----
    f32x4 acc2[2][4];
#pragma unroll
    for (int p = 0; p < 2; p++)
#pragma unroll
        for (int j = 0; j < 4; j++) acc2[p][j] = (f32x4){0.f, 0.f, 0.f, 0.f};

    for (int k0 = 0; k0 < NP224; k0 += 32) {
#pragma unroll
        for (int i = 0; i < 2; i++) {
            int chunk = w * 2 + i;
            const unsigned short* src = (chunk < 4)
                ? (vT  + ((size_t)bh * 64 + chunk * 16 + srow) * NP224)
                : (cvT + ((size_t)bh * 64 + (chunk - 4) * 16 + srow) * NP224);
            GLD(src + k0 + skoff, lB2 + chunk * 512);
        }
        __syncthreads();   // also drains our own pL ds_writes on first iter
        bf16x8 ap = *(const bf16x8*)(pL + (w * 16 + fr) * PADW + k0 + fk);
        bf16x8 ap2;
#pragma unroll
        for (int e = 0; e < 8; e++) {
            float pv = b2f((unsigned short)ap[e]);
            ap2[e] = (short)f2b(pv * pv);
        }
#pragma unroll
        for (int j = 0; j < 4; j++) {
            bf16x8 bv = *(const bf16x8*)(lB2 + (j * 16 + fr) * 32 + fk);
            bf16x8 bc = *(const bf16x8*)(lB2 + ((64 + j * 16) + fr) * 32 + fk);
            acc2[0][j] = __builtin_amdgcn_mfma_f32_16x16x32_bf16(ap,  bv, acc2[0][j], 0, 0, 0);
            acc2[1][j] = __builtin_amdgcn_mfma_f32_16x16x32_bf16(ap2, bc, acc2[1][j], 0, 0, 0);
        }
        __syncthreads();
    }

#pragma unroll
    for (int j = 0; j < 4; j++) {
        int d = j * 16 + fr;
#pragma unroll
        for (int r = 0; r < 4; r++) {
            int n = q0 + w * 16 + lr4 + r;
            if (n >= NN) continue;
            size_t o = ((size_t)(b * NN + n)) * EE + h * DD + d;
            ctxm[o] = f2b(acc2[0][j][r]);
            ctxc[o] = f2b(acc2[1][j][r]);
        }
    }
}

// =============== head: wave-per-class dot product ===============
__global__ __launch_bounds__(256) void head_kernel(
    const float* __restrict__ pooled, const float* __restrict__ W,
    const float* __restrict__ bias, float* __restrict__ out)
{
    const int wv = threadIdx.x >> 6, lane = threadIdx.x & 63;
    const int c = blockIdx.x * 4 + wv;
    const int b = blockIdx.y;
    if (c >= NCLS) return;
    const float* wr = W + (size_t)c * EE;
    const float* pr = pooled + (size_t)b * EE;
    float s = 0.f;
#pragma unroll
    for (int i = 0; i < 12; i++) s += pr[lane + i * 64] * wr[lane + i * 64];
    for (int off = 32; off > 0; off >>= 1) s += __shfl_down(s, off);
    if (lane == 0) out[(size_t)b * NCLS + c] = s + bias[c];
}

// =============== fp32 -> bf16 conversion (patch weights) ===============
__global__ __launch_bounds__(256) void cvt_kernel(
    const float* __restrict__ src, unsigned short* __restrict__ dst, int n)
{
    int i = (blockIdx.x * 256 + threadIdx.x) * 4;
    if (i >= n) return;
    float4 f = *(const float4*)(src + i);
    ushort4 u;
    u.x = f2b(f.x); u.y = f2b(f.y); u.z = f2b(f.z); u.w = f2b(f.w);
    *(ushort4*)(dst + i) = u;
}

#define W_QKV   0
#define W_PROJ  1769472
#define W_CPROJ 2359296
#define W_FC1   2949120
#define W_FC2   5308416
#define W_TOTAL 7667712

// =============== one-shot weight conversion: ALL layers ===============
__global__ __launch_bounds__(256) void cvt_all_kernel(
    const float* __restrict__ qkvw, const float* __restrict__ pw,
    const float* __restrict__ cpw, const float* __restrict__ f1,
    const float* __restrict__ f2, unsigned short* __restrict__ dst)
{
    size_t i = ((size_t)blockIdx.x * 256 + threadIdx.x) * 4;
    if (i >= (size_t)LL * W_TOTAL) return;
    int l = (int)(i / W_TOTAL);
    int r = (int)(i % W_TOTAL);
    const float* s;
    if (r < W_PROJ)        s = qkvw + (size_t)l * (3 * EE * EE) + r;
    else if (r < W_CPROJ)  s = pw   + (size_t)l * (EE * EE)     + (r - W_PROJ);
    else if (r < W_FC1)    s = cpw  + (size_t)l * (EE * EE)     + (r - W_CPROJ);
    else if (r < W_FC2)    s = f1   + (size_t)l * (MLPD * EE)   + (r - W_FC1);
    else                   s = f2   + (size_t)l * (MLPD * EE)   + (r - W_FC2);
    float4 f = *(const float4*)s;
    ushort4 u;
    u.x = f2b(f.x); u.y = f2b(f.y); u.z = f2b(f.z); u.w = f2b(f.w);
    *(ushort4*)(dst + i) = u;
}

// =============== concat qkv biases: ALL layers ===============
// bqc layout: [LL][2][2304] fp32
__global__ __launch_bounds__(256) void qkvbias_all_kernel(
    const float* __restrict__ qb, const float* __restrict__ vb,
    const float* __restrict__ cqb, const float* __restrict__ cvb,
    float* __restrict__ bqc)
{
    int l = blockIdx.y;
    int j = blockIdx.x * 256 + threadIdx.x;
    if (j >= 3 * EE) return;
    float m, c;
    if (j < EE)        { m = qb[l * EE + j];          c = cqb[l * EE + j]; }
    else if (j < 2*EE) { m = 0.f;                      c = 0.f; }
    else               { m = vb[l * EE + j - 2 * EE];  c = cvb[l * EE + j - 2 * EE]; }
    bqc[(size_t)l * 4608 + j]        = m;
    bqc[(size_t)l * 4608 + 2304 + j] = c;
}

// =============== im2col (bf16 out) ===============
__global__ __launch_bounds__(256) void im2col_kernel(
    const float* __restrict__ x, unsigned short* __restrict__ col)
{
    int idx = blockIdx.x * 256 + threadIdx.x;
    if (idx >= PROWS * EE) return;
    int c = idx % EE;
    int r = idx / EE;
    int b = r / NPATCH;
    int p = r % NPATCH;
    int ph = p / 14, pw = p % 14;
    int ch = c >> 8;
    int rem = c & 255;
    int i = rem >> 4, j = rem & 15;
    col[idx] = f2b(x[(((size_t)b * 3 + ch) * 224 + (ph * 16 + i)) * 224 + (pw * 16 + j)]);
}

// =============== assemble tokens ===============
__global__ __launch_bounds__(256) void assemble_kernel(
    const float* __restrict__ tm, const float* __restrict__ tc,
    const float* __restrict__ cls, const float* __restrict__ ccls,
    float* __restrict__ xm, float* __restrict__ xc)
{
    int idx = blockIdx.x * 256 + threadIdx.x;
    if (idx >= NROWS * EE) return;
    int e = idx % EE;
    int r = idx / EE;
    int b = r / NN, n = r % NN;
    if (n == 0) {
        xm[idx] = cls[e];
        xc[idx] = ccls[e];
    } else {
        size_t s = ((size_t)(b * NPATCH + n - 1)) * EE + e;
        xm[idx] = tm[s];
        xc[idx] = tc[s];
    }
}

// =============== merged LayerNorm for both streams (layer-0 norm1 only) ===============
__global__ __launch_bounds__(256) void ln2_kernel(
    const float* __restrict__ xm, const float* __restrict__ xc,
    unsigned short* __restrict__ y, const float* __restrict__ g,
    const float* __restrict__ bb)
{
    int row = blockIdx.x;
    int tid = threadIdx.x;
    const float* src;
    size_t orow;
    if (row < NROWS) { src = xm + (size_t)row * EE; orow = row; }
    else { src = xc + (size_t)(row - NROWS) * EE; orow = (size_t)(row - NROWS) + MPAD; }
    __shared__ float red[256];
    float v0 = src[tid], v1 = src[tid + 256], v2 = src[tid + 512];
    red[tid] = v0 + v1 + v2;
    __syncthreads();
    for (int s = 128; s > 0; s >>= 1) { if (tid < s) red[tid] += red[tid + s]; __syncthreads(); }
    float mu = red[0] * (1.f / 768.f);
    __syncthreads();
    float d0 = v0 - mu, d1 = v1 - mu, d2 = v2 - mu;
    red[tid] = d0 * d0 + d1 * d1 + d2 * d2;
    __syncthreads();
    for (int s = 128; s > 0; s >>= 1) { if (tid < s) red[tid] += red[tid + s]; __syncthreads(); }
    float rstd = rsqrtf(red[0] * (1.f / 768.f) + 1e-5f);
    unsigned short* yr = y + orow * EE;
    yr[tid]       = f2b(d0 * rstd * g[tid]       + bb[tid]);
    yr[tid + 256] = f2b(d1 * rstd * g[tid + 256] + bb[tid + 256]);
    yr[tid + 512] = f2b(d2 * rstd * g[tid + 512] + bb[tid + 512]);
}

// =============== mean-pool + LN (fp32) ===============
__global__ __launch_bounds__(256) void pool_ln_kernel(
    const float* __restrict__ xm, float* __restrict__ out,
    const float* __restrict__ g, const float* __restrict__ bb)
{
    int b = blockIdx.x;
    int tid = threadIdx.x;
    __shared__ float red[256];
    float p[3];
#pragma unroll
    for (int i = 0; i < 3; i++) {
        int e = tid + i * 256;
        float s = 0.f;
        for (int n = 1; n < NN; n++) s += xm[((size_t)(b * NN + n)) * EE + e];
        p[i] = s * (1.f / 196.f);
    }
    red[tid] = p[0] + p[1] + p[2];
    __syncthreads();
    for (int s = 128; s > 0; s >>= 1) { if (tid < s) red[tid] += red[tid + s]; __syncthreads(); }
    float mu = red[0] * (1.f / 768.f);
    __syncthreads();
    float d0 = p[0] - mu, d1 = p[1] - mu, d2 = p[2] - mu;
    red[tid] = d0 * d0 + d1 * d1 + d2 * d2;
    __syncthreads();
    for (int s = 128; s > 0; s >>= 1) { if (tid < s) red[tid] += red[tid + s]; __syncthreads(); }
    float rstd = rsqrtf(red[0] * (1.f / 768.f) + 1e-5f);
    out[(size_t)b * EE + tid]       = d0 * rstd * g[tid]       + bb[tid];
    out[(size_t)b * EE + tid + 256] = d1 * rstd * g[tid + 256] + bb[tid + 256];
    out[(size_t)b * EE + tid + 512] = d2 * rstd * g[tid + 512] + bb[tid + 512];
}

// =========================================================================
extern "C" void kernel_launch(void* const* d_in, const int* in_sizes, int n_in,
                              void* d_out, int out_size, void* d_ws, size_t ws_size,
                              hipStream_t stream)
{
    const float* x        = (const float*)d_in[0];
    const float* rpb      = (const float*)d_in[1];
    const float* patch_w  = (const float*)d_in[2];
    const float* patch_b  = (const float*)d_in[3];
    const float* cpatch_w = (const float*)d_in[4];
    const float* cpatch_b = (const float*)d_in[5];
    const float* cls_tok  = (const float*)d_in[6];
    const float* ccls_tok = (const float*)d_in[7];
    const float* norm1_g  = (const float*)d_in[8];
    const float* norm1_b  = (const float*)d_in[9];
    const float* qkv_w    = (const float*)d_in[10];
    const float* q_bias   = (const float*)d_in[11];
    const float* v_bias   = (const float*)d_in[12];
    const float* cq_bias  = (const float*)d_in[13];
    const float* cv_bias  = (const float*)d_in[14];
    const float* proj_w   = (const float*)d_in[15];
    const float* proj_b   = (const float*)d_in[16];
    const float* cproj_w  = (const float*)d_in[17];
    const float* cproj_b  = (const float*)d_in[18];
    const float* gamma1   = (const float*)d_in[19];
    const float* gamma2   = (const float*)d_in[20];
    const float* norm2_g  = (const float*)d_in[21];
    const float* norm2_b  = (const float*)d_in[22];
    const float* fc1_w    = (const float*)d_in[23];
    const float* fc1_b    = (const float*)d_in[24];
    const float* fc2_w    = (const float*)d_in[25];
    const float* fc2_b    = (const float*)d_in[26];
    const float* fcn_g    = (const float*)d_in[27];
    const float* fcn_b    = (const float*)d_in[28];
    const float* head_w   = (const float*)d_in[29];
    const float* head_b   = (const float*)d_in[30];
    float* out = (float*)d_out;

    // ---- workspace layout (~320 MB; harness fill indicates ~432 MiB available) ----
    char* base = (char*)d_ws;
    size_t off = 0;
    auto alloc = [&](size_t bytes) {
        void* p = base + off;
        off = (off + bytes + 255) & ~(size_t)255;
        return p;
    };
    unsigned short* wbuf  = (unsigned short*)alloc((size_t)LL * W_TOTAL * 2);  // 184 MB
    unsigned short* pw_m  = (unsigned short*)alloc((size_t)589824 * 2);
    unsigned short* pw_c  = (unsigned short*)alloc((size_t)589824 * 2);
    float* xm   = (float*)alloc((size_t)MPAD * EE * 4);
    float* xc   = (float*)alloc((size_t)MPAD * EE * 4);
    unsigned short* xn2 = (unsigned short*)alloc((size_t)2 * MPAD * EE * 2);
    float* qkv  = (float*)alloc((size_t)MPAD * 3 * EE * 4);
    float* cqkv = (float*)alloc((size_t)MPAD * 3 * EE * 4);
    unsigned short* hbuf = (unsigned short*)alloc((size_t)2 * MPAD * MLPD * 2);
    unsigned short* Aq  = (unsigned short*)alloc((size_t)NBH * NP256 * 128 * 2);
    unsigned short* Bk  = (unsigned short*)alloc((size_t)NBH * NP256 * 128 * 2);
    unsigned short* vT  = (unsigned short*)alloc((size_t)NBH * 64 * NP224 * 2);
    unsigned short* cvT = (unsigned short*)alloc((size_t)NBH * 64 * NP224 * 2);
    float* rsum = (float*)alloc((size_t)NBH * NP256 * 4);
    float* csum = (float*)alloc((size_t)NBH * NP256 * 4);
    unsigned short* ctx2 = (unsigned short*)alloc((size_t)2 * MPAD * EE * 2);
    unsigned short* colb = (unsigned short*)alloc((size_t)MPAD * EE * 2);
    float* bqc    = (float*)alloc((size_t)LL * 2 * 2304 * 4);
    float* pooled = (float*)alloc((size_t)BB * EE * 4);
    // split-K partial buffer: up to 2 halves x 4 splits x [MPAD][EE] fp32
    float* pbuf = (float*)alloc((size_t)2 * 4 * MPAD * EE * 4);
    // aliases
    float* tm = qkv;
    float* tc = cqkv;
    unsigned short* ctxm = ctx2;
    unsigned short* ctxc = ctx2 + (size_t)MPAD * EE;

    dim3 t256(256);
    dim3 gridRedE(MPAD * EE / 1024, 2);
    dim3 gridRedLN(MPAD, 2);

    // ---- one-shot weight + bias conversion (all layers) ----
    {
        size_t tot4 = (size_t)LL * W_TOTAL / 4;
        cvt_all_kernel<<<dim3((unsigned)((tot4 + 255) / 256)), t256, 0, stream>>>(
            qkv_w, proj_w, cproj_w, fc1_w, fc2_w, wbuf);
        qkvbias_all_kernel<<<dim3(9, LL), t256, 0, stream>>>(
            q_bias, v_bias, cq_bias, cv_bias, bqc);
    }

    // ---- patch embed (split-K S=3) ----
    cvt_kernel<<<dim3(589824 / 4 / 256), t256, 0, stream>>>(patch_w, pw_m, 589824);
    cvt_kernel<<<dim3(589824 / 4 / 256), t256, 0, stream>>>(cpatch_w, pw_c, 589824);
    im2col_kernel<<<dim3((PROWS * EE + 255) / 256), t256, 0, stream>>>(x, colb);
    mfma_gemm2_sk<<<dim3(EE / 128, 2 * HTILES, 3), t256, 0, stream>>>(
        colb, colb, pw_m, pw_c, EE, 256, EE, 3, pbuf);
    sk_reduce_kernel<<<gridRedE, t256, 0, stream>>>(
        pbuf, 3, EE, patch_b, cpatch_b, tm, tc);
    assemble_kernel<<<dim3((NROWS * EE + 255) / 256), t256, 0, stream>>>(
        tm, tc, cls_tok, ccls_tok, xm, xc);
    // layer-0 norm1
    ln2_kernel<<<dim3(2 * NROWS), t256, 0, stream>>>(xm, xc, xn2, norm1_g, norm1_b);

    dim3 gridQKV(3 * EE / 128, 2 * HTILES);
    dim3 gridMLP(MLPD / 128, 2 * HTILES);
    dim3 gridPre(4, NBH);
    dim3 gridAttn(4, NBH);
    const unsigned short* xn2c = xn2 + (size_t)MPAD * EE;
    const unsigned short* hbufc = hbuf + (size_t)MPAD * MLPD;

    for (int l = 0; l < LL; l++) {
        const unsigned short* wl = wbuf + (size_t)l * W_TOTAL;
        const float* biasq = bqc + (size_t)l * 4608;
        const float* biasc = biasq + 2304;

        // qkv dual GEMM (xn2 produced by previous layer's fc2 reduce / layer-0 ln2)
        mfma_gemm2<<<gridQKV, t256, 0, stream>>>(
            xn2, xn2c, wl + W_QKV, wl + W_QKV, biasq, biasc, EE, 3 * EE,
            MODE_F32, MODE_ELU1F, nullptr, nullptr, nullptr, qkv, cqkv, nullptr, nullptr);

        // attention: pre + fully fused wass/softmax/PV
        pre_kernel<<<gridPre, t256, 0, stream>>>(qkv, cqkv, Aq, Bk, rsum, csum, vT, cvT);
        attn_fused<<<gridAttn, t256, 0, stream>>>(Aq, Bk, rsum, csum, rpb, vT, cvT, ctxm, ctxc);

        // proj dual (split-K S=3) + reduce fused with residual AND norm2 LN
        mfma_gemm2_sk<<<dim3(EE / 128, 2 * HTILES, 3), t256, 0, stream>>>(
            ctxm, ctxc, wl + W_PROJ, wl + W_CPROJ, EE, 256, EE, 3, pbuf);
        sk_reduce_ln<<<gridRedLN, t256, 0, stream>>>(
            pbuf, 3, proj_b + l * EE, cproj_b + l * EE,
            gamma1 + l * EE, xm, xc, xm, xc,
            norm2_g + l * EE, norm2_b + l * EE, xn2);

        // MLP dual
        mfma_gemm2<<<gridMLP, t256, 0, stream>>>(
            xn2, xn2c, wl + W_FC1, wl + W_FC1, fc1_b + l * MLPD, fc1_b + l * MLPD,
            EE, MLPD, MODE_GELUB, MODE_GELUB, nullptr, nullptr, nullptr,
            nullptr, nullptr, hbuf, hbuf + (size_t)MPAD * MLPD);
        // fc2 dual (split-K S=4) + reduce fused with residual AND next layer's norm1
        mfma_gemm2_sk<<<dim3(EE / 128, 2 * HTILES, 4), t256, 0, stream>>>(
            hbuf, hbufc, wl + W_FC2, wl + W_FC2, MLPD, 768, EE, 4, pbuf);
        if (l + 1 < LL) {
            sk_reduce_ln<<<gridRedLN, t256, 0, stream>>>(
                pbuf, 4, fc2_b + l * EE, fc2_b + l * EE,
                gamma2 + l * EE, xm, xc, xm, xc,
                norm1_g + (l + 1) * EE, norm1_b + (l + 1) * EE, xn2);
        } else {
            sk_reduce_ln<<<gridRedLN, t256, 0, stream>>>(
                pbuf, 4, fc2_b + l * EE, fc2_b + l * EE,
                gamma2 + l * EE, xm, xc, xm, xc,
                nullptr, nullptr, nullptr);
        }
    }

    // ---- head ----
    pool_ln_kernel<<<dim3(BB), t256, 0, stream>>>(xm, pooled, fcn_g, fcn_b);
    head_kernel<<<dim3((NCLS + 3) / 4, BB), t256, 0, stream>>>(pooled, head_w, head_b, out);
}